// Round 2
// baseline (2858.340 us; speedup 1.0000x reference)
//
#include <hip/hip_runtime.h>

#define NN 50000
#define NE 400000
#define NBATCH 8
#define NDIM 32
#define EDIM 16
#define H 128
#define NLAYERS 3
#define EPB 64  // edges per block in edge_mlp

// ---------------- node embedding: h = x @ Wn + bn ----------------
__global__ __launch_bounds__(128) void embed_nodes_kernel(
    const float* __restrict__ x, const float* __restrict__ Wn,
    const float* __restrict__ bn, float* __restrict__ h) {
  __shared__ float Ws[NDIM * H];
  __shared__ float xs[16 * NDIM];
  int j = threadIdx.x;
  int nbase = blockIdx.x * 16;
  for (int r = 0; r < NDIM; ++r) Ws[r * H + j] = Wn[r * H + j];
#pragma unroll
  for (int t = 0; t < 4; ++t) {
    int f = j + t * 128;  // 0..511 = 16 nodes * 32 dims
    xs[f] = x[nbase * NDIM + f];
  }
  __syncthreads();
  float b = bn[j];
  for (int nn = 0; nn < 16; ++nn) {
    float acc = b;
#pragma unroll
    for (int k = 0; k < NDIM; ++k)
      acc = fmaf(xs[nn * NDIM + k], Ws[k * H + j], acc);
    h[(size_t)(nbase + nn) * H + j] = acc;
  }
}

// ---------------- degree histogram over dst ----------------
__global__ __launch_bounds__(256) void degree_kernel(const int* __restrict__ ei,
                                                     int* __restrict__ deg) {
  int e = blockIdx.x * 256 + threadIdx.x;
  if (e < NE) atomicAdd(&deg[ei[NE + e]], 1);
}

// ---------------- precompute folded edge weights ----------------
// Wm[l] : [272][128]  rows 0..255 = mW1[l][0:256], rows 256..271 = We @ mW1[l][256:384]
// bm[l] : [128]       = mb1[l] + be @ mW1[l][256:384]
__global__ __launch_bounds__(128) void precomp_wm_kernel(
    const float* __restrict__ mW1, const float* __restrict__ mb1,
    const float* __restrict__ We, const float* __restrict__ be,
    float* __restrict__ Wm, float* __restrict__ bm) {
  int l = blockIdx.x / 273;
  int r = blockIdx.x % 273;
  int j = threadIdx.x;
  const float* w1 = mW1 + (size_t)l * 384 * H;
  if (r < 256) {
    Wm[((size_t)l * 272 + r) * H + j] = w1[(size_t)r * H + j];
  } else if (r < 272) {
    int i = r - 256;
    float s = 0.f;
    for (int c = 0; c < H; ++c)
      s = fmaf(We[i * H + c], w1[(size_t)(256 + c) * H + j], s);
    Wm[((size_t)l * 272 + r) * H + j] = s;
  } else {
    float s = mb1[l * H + j];
    for (int c = 0; c < H; ++c)
      s = fmaf(be[c], w1[(size_t)(256 + c) * H + j], s);
    bm[l * H + j] = s;
  }
}

// ---------------- precompute folded update weights ----------------
// Wu[l] : [256][128] rows 0..127 = uW1[l][0:128], rows 128..255 = mW2[l] @ uW1[l][128:256]
// va[l] : [128] = mb2[l] @ uW1[l][128:256]
__global__ __launch_bounds__(128) void precomp_wu_kernel(
    const float* __restrict__ uW1, const float* __restrict__ mW2,
    const float* __restrict__ mb2, float* __restrict__ Wu,
    float* __restrict__ va) {
  int l = blockIdx.x / 257;
  int r = blockIdx.x % 257;
  int j = threadIdx.x;
  const float* u1 = uW1 + (size_t)l * 256 * H;
  if (r < 128) {
    Wu[((size_t)l * 256 + r) * H + j] = u1[(size_t)r * H + j];
  } else if (r < 256) {
    int i = r - 128;
    const float* m2 = mW2 + ((size_t)l * H + i) * H;
    float s = 0.f;
    for (int c = 0; c < H; ++c)
      s = fmaf(m2[c], u1[(size_t)(128 + c) * H + j], s);
    Wu[((size_t)l * 256 + r) * H + j] = s;
  } else {
    float s = 0.f;
    for (int c = 0; c < H; ++c)
      s = fmaf(mb2[l * H + c], u1[(size_t)(128 + c) * H + j], s);
    va[l * H + j] = s;
  }
}

// ---------------- fused edge MLP + scatter-add of relu(hidden) ----------------
// 64 edges/block, 256 threads; thread tile = 8 edges x 4 cols.
// Weights double-buffered through LDS (8 k-rows per chunk).
__global__ __launch_bounds__(256, 2) void edge_mlp_kernel(
    const float* __restrict__ h, const int* __restrict__ ei,
    const float* __restrict__ ea, const float* __restrict__ Wm,
    const float* __restrict__ bm, float* __restrict__ aggrH) {
  __shared__ float ins[EPB][272];     // [h_dst(128) | h_src(128) | ea(16)]
  __shared__ float wbuf[2][8][H];     // k-chunk of weights, double buffered
  __shared__ int srcS[EPB], dstS[EPB];
  int tid = threadIdx.x;
  int ebase = blockIdx.x * EPB;
  if (tid < EPB) srcS[tid] = ei[ebase + tid];
  else if (tid < 2 * EPB) dstS[tid - EPB] = ei[NE + ebase + tid - EPB];
  __syncthreads();
  // stage h[dst] and h[src] rows (lanes 0..31 of each row-octet read 512B contiguous)
  {
    int r = tid >> 5, c = tid & 31;
#pragma unroll
    for (int i = 0; i < 8; ++i) {
      int rr = r + i * 8;
      float4 v = ((const float4*)(h + (size_t)dstS[rr] * H))[c];
      *(float4*)&ins[rr][c * 4] = v;
    }
#pragma unroll
    for (int i = 0; i < 8; ++i) {
      int rr = r + i * 8;
      float4 v = ((const float4*)(h + (size_t)srcS[rr] * H))[c];
      *(float4*)&ins[rr][H + c * 4] = v;
    }
  }
  // stage edge attrs (coalesced)
  {
    int r = tid >> 2, c = tid & 3;
    float4 v = ((const float4*)ea)[(size_t)(ebase + r) * 4 + c];
    *(float4*)&ins[r][2 * H + c * 4] = v;
  }
  // prefetch weight chunk 0
  int wr = tid >> 5, wc = tid & 31;
  *(float4*)&wbuf[0][wr][wc * 4] = ((const float4*)(Wm + (size_t)wr * H))[wc];

  int cg = tid & 31;         // column group: cols cg*4 .. cg*4+3
  int e0 = (tid >> 5) * 8;   // 8 edges per thread
  float4 acc[8];
  float4 bias = ((const float4*)bm)[cg];
#pragma unroll
  for (int e = 0; e < 8; ++e) acc[e] = bias;
  __syncthreads();

  for (int kc = 0; kc < 34; ++kc) {
    int buf = kc & 1;
    if (kc + 1 < 34) {
      int kb = (kc + 1) * 8;
      *(float4*)&wbuf[buf ^ 1][wr][wc * 4] =
          ((const float4*)(Wm + (size_t)(kb + wr) * H))[wc];
    }
    int k0 = kc * 8;
#pragma unroll
    for (int q = 0; q < 2; ++q) {
      int kq = k0 + q * 4;
      float4 w0 = *(float4*)&wbuf[buf][q * 4 + 0][cg * 4];
      float4 w1 = *(float4*)&wbuf[buf][q * 4 + 1][cg * 4];
      float4 w2 = *(float4*)&wbuf[buf][q * 4 + 2][cg * 4];
      float4 w3 = *(float4*)&wbuf[buf][q * 4 + 3][cg * 4];
#pragma unroll
      for (int e = 0; e < 8; ++e) {
        float4 a = *(const float4*)&ins[e0 + e][kq];
        acc[e].x = fmaf(a.x, w0.x, acc[e].x);
        acc[e].y = fmaf(a.x, w0.y, acc[e].y);
        acc[e].z = fmaf(a.x, w0.z, acc[e].z);
        acc[e].w = fmaf(a.x, w0.w, acc[e].w);
        acc[e].x = fmaf(a.y, w1.x, acc[e].x);
        acc[e].y = fmaf(a.y, w1.y, acc[e].y);
        acc[e].z = fmaf(a.y, w1.z, acc[e].z);
        acc[e].w = fmaf(a.y, w1.w, acc[e].w);
        acc[e].x = fmaf(a.z, w2.x, acc[e].x);
        acc[e].y = fmaf(a.z, w2.y, acc[e].y);
        acc[e].z = fmaf(a.z, w2.z, acc[e].z);
        acc[e].w = fmaf(a.z, w2.w, acc[e].w);
        acc[e].x = fmaf(a.w, w3.x, acc[e].x);
        acc[e].y = fmaf(a.w, w3.y, acc[e].y);
        acc[e].z = fmaf(a.w, w3.z, acc[e].z);
        acc[e].w = fmaf(a.w, w3.w, acc[e].w);
      }
    }
    __syncthreads();
  }
#pragma unroll
  for (int e = 0; e < 8; ++e) {
    float* dp = aggrH + (size_t)dstS[e0 + e] * H + cg * 4;
    unsafeAtomicAdd(dp + 0, fmaxf(acc[e].x, 0.f));
    unsafeAtomicAdd(dp + 1, fmaxf(acc[e].y, 0.f));
    unsafeAtomicAdd(dp + 2, fmaxf(acc[e].z, 0.f));
    unsafeAtomicAdd(dp + 3, fmaxf(acc[e].w, 0.f));
  }
}

// ---------------- fused node update ----------------
__global__ __launch_bounds__(256) void node_update_kernel(
    float* __restrict__ h, const float* __restrict__ aggrH,
    const int* __restrict__ deg, const float* __restrict__ Wu,
    const float* __restrict__ va, const float* __restrict__ ub1,
    const float* __restrict__ uW2, const float* __restrict__ ub2) {
  __shared__ float ins[16][256];  // [h(128) | aggrH(128)]
  __shared__ float ts[16][128];
  __shared__ float degS[16];
  int tid = threadIdx.x;
  int nbase = blockIdx.x * 16;
  if (tid < 16) degS[tid] = (float)deg[nbase + tid];
#pragma unroll
  for (int t = 0; t < 4; ++t) {
    int f = tid + t * 256;
    int r = f >> 5, c4 = f & 31;
    const float* s = (r < 16) ? (h + (size_t)(nbase + r) * H)
                              : (aggrH + (size_t)(nbase + r - 16) * H);
    float4 v = ((const float4*)s)[c4];
    float* q = (r < 16) ? &ins[r][c4 * 4] : &ins[r - 16][H + c4 * 4];
    *(float4*)q = v;
  }
  __syncthreads();
  int j = tid & 127;
  int n0 = (tid >> 7) * 8;
  float acc[8];
  {
    float b = ub1[j], vaj = va[j];
#pragma unroll
    for (int e = 0; e < 8; ++e) acc[e] = fmaf(degS[n0 + e], vaj, b);
  }
  for (int k = 0; k < 256; k += 4) {
    float w0 = Wu[(size_t)(k + 0) * H + j];
    float w1 = Wu[(size_t)(k + 1) * H + j];
    float w2 = Wu[(size_t)(k + 2) * H + j];
    float w3 = Wu[(size_t)(k + 3) * H + j];
#pragma unroll
    for (int e = 0; e < 8; ++e) {
      float4 v = *(const float4*)&ins[n0 + e][k];
      acc[e] = fmaf(v.x, w0, acc[e]);
      acc[e] = fmaf(v.y, w1, acc[e]);
      acc[e] = fmaf(v.z, w2, acc[e]);
      acc[e] = fmaf(v.w, w3, acc[e]);
    }
  }
#pragma unroll
  for (int e = 0; e < 8; ++e) ts[n0 + e][j] = fmaxf(acc[e], 0.f);
  __syncthreads();
  {
    float b2 = ub2[j];
#pragma unroll
    for (int e = 0; e < 8; ++e) acc[e] = b2;
  }
  for (int k = 0; k < 128; k += 4) {
    float w0 = uW2[(size_t)(k + 0) * H + j];
    float w1 = uW2[(size_t)(k + 1) * H + j];
    float w2 = uW2[(size_t)(k + 2) * H + j];
    float w3 = uW2[(size_t)(k + 3) * H + j];
#pragma unroll
    for (int e = 0; e < 8; ++e) {
      float4 v = *(const float4*)&ts[n0 + e][k];
      acc[e] = fmaf(v.x, w0, acc[e]);
      acc[e] = fmaf(v.y, w1, acc[e]);
      acc[e] = fmaf(v.z, w2, acc[e]);
      acc[e] = fmaf(v.w, w3, acc[e]);
    }
  }
#pragma unroll
  for (int e = 0; e < 8; ++e) {
    size_t idx = (size_t)(nbase + n0 + e) * H + j;
    h[idx] += acc[e];
  }
}

// ---------------- batch mean pooling (batch is sorted) ----------------
__global__ __launch_bounds__(128) void pool_kernel(
    const float* __restrict__ h, const int* __restrict__ batch,
    float* __restrict__ pooled, int* __restrict__ counts) {
  int j = threadIdx.x;
  int nbase = blockIdx.x * 128;
  int nend = nbase + 128;
  if (nend > NN) nend = NN;
  int cur = batch[nbase];
  float sum = 0.f;
  int cnt = 0;
  for (int n = nbase; n < nend; ++n) {
    int b = batch[n];
    if (b != cur) {
      unsafeAtomicAdd(&pooled[cur * H + j], sum);
      if (j == 0) atomicAdd(&counts[cur], cnt);
      sum = 0.f; cnt = 0; cur = b;
    }
    sum += h[(size_t)n * H + j];
    cnt++;
  }
  unsafeAtomicAdd(&pooled[cur * H + j], sum);
  if (j == 0) atomicAdd(&counts[cur], cnt);
}

// ---------------- readout MLP ----------------
__global__ __launch_bounds__(128) void readout_kernel(
    const float* __restrict__ pooled, const int* __restrict__ counts,
    const float* __restrict__ gf, const float* __restrict__ Wg,
    const float* __restrict__ bg, const float* __restrict__ rW1,
    const float* __restrict__ rb1, const float* __restrict__ rW2,
    const float* __restrict__ rb2, const float* __restrict__ rW3,
    const float* __restrict__ rb3, float* __restrict__ out) {
  __shared__ float fin[256];
  __shared__ float t1[128];
  __shared__ float t2[64];
  int j = threadIdx.x;
  for (int b = 0; b < NBATCH; ++b) {
    float cnt = (float)counts[b];
    if (cnt < 1.f) cnt = 1.f;
    fin[j] = pooled[b * H + j] / cnt;
    fin[H + j] = fmaf(gf[b], Wg[j], bg[j]);
    __syncthreads();
    float a = rb1[j];
    for (int k = 0; k < 256; ++k) a = fmaf(fin[k], rW1[k * H + j], a);
    t1[j] = fmaxf(a, 0.f);
    __syncthreads();
    if (j < 64) {
      float a2 = rb2[j];
      for (int k = 0; k < 128; ++k) a2 = fmaf(t1[k], rW2[k * 64 + j], a2);
      t2[j] = fmaxf(a2, 0.f);
    }
    __syncthreads();
    if (j < 64) {
      float p = t2[j] * rW3[j];
#pragma unroll
      for (int off = 32; off; off >>= 1) p += __shfl_down(p, off);
      if (j == 0) out[b] = p + rb3[0];
    }
    __syncthreads();
  }
}

extern "C" void kernel_launch(void* const* d_in, const int* in_sizes, int n_in,
                              void* d_out, int out_size, void* d_ws, size_t ws_size,
                              hipStream_t stream) {
  const float* x   = (const float*)d_in[0];
  const float* ea  = (const float*)d_in[1];
  const float* gf  = (const float*)d_in[2];
  const int*   ei  = (const int*)d_in[3];
  const int*   bat = (const int*)d_in[4];
  const float* Wn  = (const float*)d_in[5];
  const float* bn  = (const float*)d_in[6];
  const float* We  = (const float*)d_in[7];
  const float* be  = (const float*)d_in[8];
  const float* Wg  = (const float*)d_in[9];
  const float* bg  = (const float*)d_in[10];
  const float* mW1 = (const float*)d_in[11];
  const float* mb1 = (const float*)d_in[12];
  const float* mW2 = (const float*)d_in[13];
  const float* mb2 = (const float*)d_in[14];
  const float* uW1 = (const float*)d_in[15];
  const float* ub1 = (const float*)d_in[16];
  const float* uW2 = (const float*)d_in[17];
  const float* ub2 = (const float*)d_in[18];
  const float* rW1 = (const float*)d_in[19];
  const float* rb1 = (const float*)d_in[20];
  const float* rW2 = (const float*)d_in[21];
  const float* rb2 = (const float*)d_in[22];
  const float* rW3 = (const float*)d_in[23];
  const float* rb3 = (const float*)d_in[24];

  char* p = (char*)d_ws;
  float* h     = (float*)p; p += (size_t)NN * H * 4;        // 25.6 MB
  float* aggrH = (float*)p; p += (size_t)NN * H * 4;        // 25.6 MB
  float* Wm    = (float*)p; p += (size_t)NLAYERS * 272 * H * 4;
  float* bm    = (float*)p; p += (size_t)NLAYERS * H * 4;
  float* Wu    = (float*)p; p += (size_t)NLAYERS * 256 * H * 4;
  float* va    = (float*)p; p += (size_t)NLAYERS * H * 4;
  int*   deg   = (int*)p;   p += (size_t)NN * 4;
  float* pooled= (float*)p; p += (size_t)NBATCH * H * 4;
  int*   counts= (int*)p;   p += 64;

  hipMemsetAsync(deg, 0, (size_t)NN * 4, stream);
  hipMemsetAsync(pooled, 0, (size_t)NBATCH * H * 4, stream);
  hipMemsetAsync(counts, 0, 64, stream);

  embed_nodes_kernel<<<NN / 16, 128, 0, stream>>>(x, Wn, bn, h);
  degree_kernel<<<(NE + 255) / 256, 256, 0, stream>>>(ei, deg);
  precomp_wm_kernel<<<NLAYERS * 273, 128, 0, stream>>>(mW1, mb1, We, be, Wm, bm);
  precomp_wu_kernel<<<NLAYERS * 257, 128, 0, stream>>>(uW1, mW2, mb2, Wu, va);

  for (int l = 0; l < NLAYERS; ++l) {
    hipMemsetAsync(aggrH, 0, (size_t)NN * H * 4, stream);
    edge_mlp_kernel<<<NE / EPB, 256, 0, stream>>>(
        h, ei, ea, Wm + (size_t)l * 272 * H, bm + (size_t)l * H, aggrH);
    node_update_kernel<<<NN / 16, 256, 0, stream>>>(
        h, aggrH, deg, Wu + (size_t)l * 256 * H, va + (size_t)l * H,
        ub1 + (size_t)l * H, uW2 + (size_t)l * H * H, ub2 + (size_t)l * H);
  }

  pool_kernel<<<(NN + 127) / 128, 128, 0, stream>>>(h, bat, pooled, counts);
  readout_kernel<<<1, 128, 0, stream>>>(pooled, counts, gf, Wg, bg, rW1, rb1,
                                        rW2, rb2, rW3, rb3, (float*)d_out);
}

// Round 3
// 1770.570 us; speedup vs baseline: 1.6144x; 1.6144x over previous
//
#include <hip/hip_runtime.h>

#define NN 50000
#define NE 400000
#define NBATCH 8
#define NDIM 32
#define EDIM 16
#define H 128
#define NLAYERS 3
#define EPB 64  // edges per block in edge_mlp

// ---------------- node embedding: h = x @ Wn + bn ----------------
__global__ __launch_bounds__(128) void embed_nodes_kernel(
    const float* __restrict__ x, const float* __restrict__ Wn,
    const float* __restrict__ bn, float* __restrict__ h) {
  __shared__ float Ws[NDIM * H];
  __shared__ float xs[16 * NDIM];
  int j = threadIdx.x;
  int nbase = blockIdx.x * 16;
  for (int r = 0; r < NDIM; ++r) Ws[r * H + j] = Wn[r * H + j];
#pragma unroll
  for (int t = 0; t < 4; ++t) {
    int f = j + t * 128;  // 0..511 = 16 nodes * 32 dims
    xs[f] = x[nbase * NDIM + f];
  }
  __syncthreads();
  float b = bn[j];
  for (int nn = 0; nn < 16; ++nn) {
    float acc = b;
#pragma unroll
    for (int k = 0; k < NDIM; ++k)
      acc = fmaf(xs[nn * NDIM + k], Ws[k * H + j], acc);
    h[(size_t)(nbase + nn) * H + j] = acc;
  }
}

// ---------------- degree histogram over dst ----------------
__global__ __launch_bounds__(256) void degree_kernel(const int* __restrict__ ei,
                                                     int* __restrict__ deg) {
  int e = blockIdx.x * 256 + threadIdx.x;
  if (e < NE) atomicAdd(&deg[ei[NE + e]], 1);
}

// ---------------- precompute folded edge weights ----------------
// Wm[l] : [272][128]  rows 0..255 = mW1[l][0:256], rows 256..271 = We @ mW1[l][256:384]
// bm[l] : [128]       = mb1[l] + be @ mW1[l][256:384]
__global__ __launch_bounds__(128) void precomp_wm_kernel(
    const float* __restrict__ mW1, const float* __restrict__ mb1,
    const float* __restrict__ We, const float* __restrict__ be,
    float* __restrict__ Wm, float* __restrict__ bm) {
  int l = blockIdx.x / 273;
  int r = blockIdx.x % 273;
  int j = threadIdx.x;
  const float* w1 = mW1 + (size_t)l * 384 * H;
  if (r < 256) {
    Wm[((size_t)l * 272 + r) * H + j] = w1[(size_t)r * H + j];
  } else if (r < 272) {
    int i = r - 256;
    float s = 0.f;
    for (int c = 0; c < H; ++c)
      s = fmaf(We[i * H + c], w1[(size_t)(256 + c) * H + j], s);
    Wm[((size_t)l * 272 + r) * H + j] = s;
  } else {
    float s = mb1[l * H + j];
    for (int c = 0; c < H; ++c)
      s = fmaf(be[c], w1[(size_t)(256 + c) * H + j], s);
    bm[l * H + j] = s;
  }
}

// ---------------- precompute folded update weights ----------------
// Wu[l] : [256][128] rows 0..127 = uW1[l][0:128], rows 128..255 = mW2[l] @ uW1[l][128:256]
// va[l] : [128] = mb2[l] @ uW1[l][128:256]
__global__ __launch_bounds__(128) void precomp_wu_kernel(
    const float* __restrict__ uW1, const float* __restrict__ mW2,
    const float* __restrict__ mb2, float* __restrict__ Wu,
    float* __restrict__ va) {
  int l = blockIdx.x / 257;
  int r = blockIdx.x % 257;
  int j = threadIdx.x;
  const float* u1 = uW1 + (size_t)l * 256 * H;
  if (r < 128) {
    Wu[((size_t)l * 256 + r) * H + j] = u1[(size_t)r * H + j];
  } else if (r < 256) {
    int i = r - 128;
    const float* m2 = mW2 + ((size_t)l * H + i) * H;
    float s = 0.f;
    for (int c = 0; c < H; ++c)
      s = fmaf(m2[c], u1[(size_t)(128 + c) * H + j], s);
    Wu[((size_t)l * 256 + r) * H + j] = s;
  } else {
    float s = 0.f;
    for (int c = 0; c < H; ++c)
      s = fmaf(mb2[l * H + c], u1[(size_t)(128 + c) * H + j], s);
    va[l * H + j] = s;
  }
}

// ---------------- fused edge MLP + scatter-add of relu(hidden) ----------------
// 64 edges/block, 256 threads; thread tile = 8 edges x 4 cols.
// Weights double-buffered through LDS; epilogue transposes through LDS so
// atomics are column-contiguous per wave (coalesced RMW).
__global__ __launch_bounds__(256, 2) void edge_mlp_kernel(
    const float* __restrict__ h, const int* __restrict__ ei,
    const float* __restrict__ ea, const float* __restrict__ Wm,
    const float* __restrict__ bm, float* __restrict__ aggrH) {
  __shared__ float ins[EPB][272];     // [h_dst(128) | h_src(128) | ea(16)]; reused as ts[64][128]
  __shared__ float wbuf[2][8][H];     // k-chunk of weights, double buffered
  __shared__ int srcS[EPB], dstS[EPB];
  int tid = threadIdx.x;
  int ebase = blockIdx.x * EPB;
  if (tid < EPB) srcS[tid] = ei[ebase + tid];
  else if (tid < 2 * EPB) dstS[tid - EPB] = ei[NE + ebase + tid - EPB];
  __syncthreads();
  // stage h[dst] and h[src] rows
  {
    int r = tid >> 5, c = tid & 31;
#pragma unroll
    for (int i = 0; i < 8; ++i) {
      int rr = r + i * 8;
      float4 v = ((const float4*)(h + (size_t)dstS[rr] * H))[c];
      *(float4*)&ins[rr][c * 4] = v;
    }
#pragma unroll
    for (int i = 0; i < 8; ++i) {
      int rr = r + i * 8;
      float4 v = ((const float4*)(h + (size_t)srcS[rr] * H))[c];
      *(float4*)&ins[rr][H + c * 4] = v;
    }
  }
  // stage edge attrs (coalesced)
  {
    int r = tid >> 2, c = tid & 3;
    float4 v = ((const float4*)ea)[(size_t)(ebase + r) * 4 + c];
    *(float4*)&ins[r][2 * H + c * 4] = v;
  }
  // prefetch weight chunk 0
  int wr = tid >> 5, wc = tid & 31;
  *(float4*)&wbuf[0][wr][wc * 4] = ((const float4*)(Wm + (size_t)wr * H))[wc];

  int cg = tid & 31;         // column group: cols cg*4 .. cg*4+3
  int e0 = (tid >> 5) * 8;   // 8 edges per thread
  float4 acc[8];
  float4 bias = ((const float4*)bm)[cg];
#pragma unroll
  for (int e = 0; e < 8; ++e) acc[e] = bias;
  __syncthreads();

  for (int kc = 0; kc < 34; ++kc) {
    int buf = kc & 1;
    if (kc + 1 < 34) {
      int kb = (kc + 1) * 8;
      *(float4*)&wbuf[buf ^ 1][wr][wc * 4] =
          ((const float4*)(Wm + (size_t)(kb + wr) * H))[wc];
    }
    int k0 = kc * 8;
#pragma unroll
    for (int q = 0; q < 2; ++q) {
      int kq = k0 + q * 4;
      float4 w0 = *(float4*)&wbuf[buf][q * 4 + 0][cg * 4];
      float4 w1 = *(float4*)&wbuf[buf][q * 4 + 1][cg * 4];
      float4 w2 = *(float4*)&wbuf[buf][q * 4 + 2][cg * 4];
      float4 w3 = *(float4*)&wbuf[buf][q * 4 + 3][cg * 4];
#pragma unroll
      for (int e = 0; e < 8; ++e) {
        float4 a = *(const float4*)&ins[e0 + e][kq];
        acc[e].x = fmaf(a.x, w0.x, acc[e].x);
        acc[e].y = fmaf(a.x, w0.y, acc[e].y);
        acc[e].z = fmaf(a.x, w0.z, acc[e].z);
        acc[e].w = fmaf(a.x, w0.w, acc[e].w);
        acc[e].x = fmaf(a.y, w1.x, acc[e].x);
        acc[e].y = fmaf(a.y, w1.y, acc[e].y);
        acc[e].z = fmaf(a.y, w1.z, acc[e].z);
        acc[e].w = fmaf(a.y, w1.w, acc[e].w);
        acc[e].x = fmaf(a.z, w2.x, acc[e].x);
        acc[e].y = fmaf(a.z, w2.y, acc[e].y);
        acc[e].z = fmaf(a.z, w2.z, acc[e].z);
        acc[e].w = fmaf(a.z, w2.w, acc[e].w);
        acc[e].x = fmaf(a.w, w3.x, acc[e].x);
        acc[e].y = fmaf(a.w, w3.y, acc[e].y);
        acc[e].z = fmaf(a.w, w3.z, acc[e].z);
        acc[e].w = fmaf(a.w, w3.w, acc[e].w);
      }
    }
    __syncthreads();
  }

  // Epilogue: relu -> LDS transpose (reuse ins) -> coalesced atomics.
  float* ts = &ins[0][0];  // 64*128 floats; ins is dead after final barrier
#pragma unroll
  for (int e = 0; e < 8; ++e) {
    float4 r;
    r.x = fmaxf(acc[e].x, 0.f);
    r.y = fmaxf(acc[e].y, 0.f);
    r.z = fmaxf(acc[e].z, 0.f);
    r.w = fmaxf(acc[e].w, 0.f);
    *(float4*)&ts[(e0 + e) * H + cg * 4] = r;
  }
  __syncthreads();
  {
    int j = tid & 127;
    int er0 = (tid >> 7) * 32;  // threads 0..127 -> edges 0..31, 128..255 -> 32..63
#pragma unroll
    for (int e = 0; e < 32; ++e) {
      int ee = er0 + e;
      unsafeAtomicAdd(&aggrH[(size_t)dstS[ee] * H + j], ts[ee * H + j]);
    }
  }
}

// ---------------- fused node update ----------------
__global__ __launch_bounds__(256) void node_update_kernel(
    float* __restrict__ h, const float* __restrict__ aggrH,
    const int* __restrict__ deg, const float* __restrict__ Wu,
    const float* __restrict__ va, const float* __restrict__ ub1,
    const float* __restrict__ uW2, const float* __restrict__ ub2) {
  __shared__ float ins[16][256];  // [h(128) | aggrH(128)]
  __shared__ float ts[16][128];
  __shared__ float degS[16];
  int tid = threadIdx.x;
  int nbase = blockIdx.x * 16;
  if (tid < 16) degS[tid] = (float)deg[nbase + tid];
#pragma unroll
  for (int t = 0; t < 4; ++t) {
    int f = tid + t * 256;
    int r = f >> 5, c4 = f & 31;
    const float* s = (r < 16) ? (h + (size_t)(nbase + r) * H)
                              : (aggrH + (size_t)(nbase + r - 16) * H);
    float4 v = ((const float4*)s)[c4];
    float* q = (r < 16) ? &ins[r][c4 * 4] : &ins[r - 16][H + c4 * 4];
    *(float4*)q = v;
  }
  __syncthreads();
  int j = tid & 127;
  int n0 = (tid >> 7) * 8;
  float acc[8];
  {
    float b = ub1[j], vaj = va[j];
#pragma unroll
    for (int e = 0; e < 8; ++e) acc[e] = fmaf(degS[n0 + e], vaj, b);
  }
  for (int k = 0; k < 256; k += 4) {
    float w0 = Wu[(size_t)(k + 0) * H + j];
    float w1 = Wu[(size_t)(k + 1) * H + j];
    float w2 = Wu[(size_t)(k + 2) * H + j];
    float w3 = Wu[(size_t)(k + 3) * H + j];
#pragma unroll
    for (int e = 0; e < 8; ++e) {
      float4 v = *(const float4*)&ins[n0 + e][k];
      acc[e] = fmaf(v.x, w0, acc[e]);
      acc[e] = fmaf(v.y, w1, acc[e]);
      acc[e] = fmaf(v.z, w2, acc[e]);
      acc[e] = fmaf(v.w, w3, acc[e]);
    }
  }
#pragma unroll
  for (int e = 0; e < 8; ++e) ts[n0 + e][j] = fmaxf(acc[e], 0.f);
  __syncthreads();
  {
    float b2 = ub2[j];
#pragma unroll
    for (int e = 0; e < 8; ++e) acc[e] = b2;
  }
  for (int k = 0; k < 128; k += 4) {
    float w0 = uW2[(size_t)(k + 0) * H + j];
    float w1 = uW2[(size_t)(k + 1) * H + j];
    float w2 = uW2[(size_t)(k + 2) * H + j];
    float w3 = uW2[(size_t)(k + 3) * H + j];
#pragma unroll
    for (int e = 0; e < 8; ++e) {
      float4 v = *(const float4*)&ts[n0 + e][k];
      acc[e] = fmaf(v.x, w0, acc[e]);
      acc[e] = fmaf(v.y, w1, acc[e]);
      acc[e] = fmaf(v.z, w2, acc[e]);
      acc[e] = fmaf(v.w, w3, acc[e]);
    }
  }
#pragma unroll
  for (int e = 0; e < 8; ++e) {
    size_t idx = (size_t)(nbase + n0 + e) * H + j;
    h[idx] += acc[e];
  }
}

// ---------------- batch mean pooling (batch is sorted) ----------------
__global__ __launch_bounds__(128) void pool_kernel(
    const float* __restrict__ h, const int* __restrict__ batch,
    float* __restrict__ pooled, int* __restrict__ counts) {
  int j = threadIdx.x;
  int nbase = blockIdx.x * 128;
  int nend = nbase + 128;
  if (nend > NN) nend = NN;
  int cur = batch[nbase];
  float sum = 0.f;
  int cnt = 0;
  for (int n = nbase; n < nend; ++n) {
    int b = batch[n];
    if (b != cur) {
      unsafeAtomicAdd(&pooled[cur * H + j], sum);
      if (j == 0) atomicAdd(&counts[cur], cnt);
      sum = 0.f; cnt = 0; cur = b;
    }
    sum += h[(size_t)n * H + j];
    cnt++;
  }
  unsafeAtomicAdd(&pooled[cur * H + j], sum);
  if (j == 0) atomicAdd(&counts[cur], cnt);
}

// ---------------- readout MLP ----------------
__global__ __launch_bounds__(128) void readout_kernel(
    const float* __restrict__ pooled, const int* __restrict__ counts,
    const float* __restrict__ gf, const float* __restrict__ Wg,
    const float* __restrict__ bg, const float* __restrict__ rW1,
    const float* __restrict__ rb1, const float* __restrict__ rW2,
    const float* __restrict__ rb2, const float* __restrict__ rW3,
    const float* __restrict__ rb3, float* __restrict__ out) {
  __shared__ float fin[256];
  __shared__ float t1[128];
  __shared__ float t2[64];
  int j = threadIdx.x;
  for (int b = 0; b < NBATCH; ++b) {
    float cnt = (float)counts[b];
    if (cnt < 1.f) cnt = 1.f;
    fin[j] = pooled[b * H + j] / cnt;
    fin[H + j] = fmaf(gf[b], Wg[j], bg[j]);
    __syncthreads();
    float a = rb1[j];
    for (int k = 0; k < 256; ++k) a = fmaf(fin[k], rW1[k * H + j], a);
    t1[j] = fmaxf(a, 0.f);
    __syncthreads();
    if (j < 64) {
      float a2 = rb2[j];
      for (int k = 0; k < 128; ++k) a2 = fmaf(t1[k], rW2[k * 64 + j], a2);
      t2[j] = fmaxf(a2, 0.f);
    }
    __syncthreads();
    if (j < 64) {
      float p = t2[j] * rW3[j];
#pragma unroll
      for (int off = 32; off; off >>= 1) p += __shfl_down(p, off);
      if (j == 0) out[b] = p + rb3[0];
    }
    __syncthreads();
  }
}

extern "C" void kernel_launch(void* const* d_in, const int* in_sizes, int n_in,
                              void* d_out, int out_size, void* d_ws, size_t ws_size,
                              hipStream_t stream) {
  const float* x   = (const float*)d_in[0];
  const float* ea  = (const float*)d_in[1];
  const float* gf  = (const float*)d_in[2];
  const int*   ei  = (const int*)d_in[3];
  const int*   bat = (const int*)d_in[4];
  const float* Wn  = (const float*)d_in[5];
  const float* bn  = (const float*)d_in[6];
  const float* We  = (const float*)d_in[7];
  const float* be  = (const float*)d_in[8];
  const float* Wg  = (const float*)d_in[9];
  const float* bg  = (const float*)d_in[10];
  const float* mW1 = (const float*)d_in[11];
  const float* mb1 = (const float*)d_in[12];
  const float* mW2 = (const float*)d_in[13];
  const float* mb2 = (const float*)d_in[14];
  const float* uW1 = (const float*)d_in[15];
  const float* ub1 = (const float*)d_in[16];
  const float* uW2 = (const float*)d_in[17];
  const float* ub2 = (const float*)d_in[18];
  const float* rW1 = (const float*)d_in[19];
  const float* rb1 = (const float*)d_in[20];
  const float* rW2 = (const float*)d_in[21];
  const float* rb2 = (const float*)d_in[22];
  const float* rW3 = (const float*)d_in[23];
  const float* rb3 = (const float*)d_in[24];

  char* p = (char*)d_ws;
  float* h     = (float*)p; p += (size_t)NN * H * 4;        // 25.6 MB
  float* aggrH = (float*)p; p += (size_t)NN * H * 4;        // 25.6 MB
  float* Wm    = (float*)p; p += (size_t)NLAYERS * 272 * H * 4;
  float* bm    = (float*)p; p += (size_t)NLAYERS * H * 4;
  float* Wu    = (float*)p; p += (size_t)NLAYERS * 256 * H * 4;
  float* va    = (float*)p; p += (size_t)NLAYERS * H * 4;
  int*   deg   = (int*)p;   p += (size_t)NN * 4;
  float* pooled= (float*)p; p += (size_t)NBATCH * H * 4;
  int*   counts= (int*)p;   p += 64;

  hipMemsetAsync(deg, 0, (size_t)NN * 4, stream);
  hipMemsetAsync(pooled, 0, (size_t)NBATCH * H * 4, stream);
  hipMemsetAsync(counts, 0, 64, stream);

  embed_nodes_kernel<<<NN / 16, 128, 0, stream>>>(x, Wn, bn, h);
  degree_kernel<<<(NE + 255) / 256, 256, 0, stream>>>(ei, deg);
  precomp_wm_kernel<<<NLAYERS * 273, 128, 0, stream>>>(mW1, mb1, We, be, Wm, bm);
  precomp_wu_kernel<<<NLAYERS * 257, 128, 0, stream>>>(uW1, mW2, mb2, Wu, va);

  for (int l = 0; l < NLAYERS; ++l) {
    hipMemsetAsync(aggrH, 0, (size_t)NN * H * 4, stream);
    edge_mlp_kernel<<<NE / EPB, 256, 0, stream>>>(
        h, ei, ea, Wm + (size_t)l * 272 * H, bm + (size_t)l * H, aggrH);
    node_update_kernel<<<NN / 16, 256, 0, stream>>>(
        h, aggrH, deg, Wu + (size_t)l * 256 * H, va + (size_t)l * H,
        ub1 + (size_t)l * H, uW2 + (size_t)l * H * H, ub2 + (size_t)l * H);
  }

  pool_kernel<<<(NN + 127) / 128, 128, 0, stream>>>(h, bat, pooled, counts);
  readout_kernel<<<1, 128, 0, stream>>>(pooled, counts, gf, Wg, bg, rW1, rb1,
                                        rW2, rb2, rW3, rb3, (float*)d_out);
}

// Round 4
// 1224.098 us; speedup vs baseline: 2.3351x; 1.4464x over previous
//
#include <hip/hip_runtime.h>

#define NN 50000
#define NE 400000
#define NBATCH 8
#define NDIM 32
#define EDIM 16
#define H 128
#define NLAYERS 3
#define EPB 128   // edges per block in edge_mlp (4 waves x 32 edges)
#define KTOT 272  // folded K: 128 dst + 128 src + 16 edge-attr

typedef __attribute__((ext_vector_type(8))) __bf16 bf16x8;
typedef __attribute__((ext_vector_type(16))) float f32x16;
typedef __attribute__((ext_vector_type(8))) short short8;

// ---------------- node embedding: h = x @ Wn + bn ----------------
__global__ __launch_bounds__(128) void embed_nodes_kernel(
    const float* __restrict__ x, const float* __restrict__ Wn,
    const float* __restrict__ bn, float* __restrict__ h) {
  __shared__ float Ws[NDIM * H];
  __shared__ float xs[16 * NDIM];
  int j = threadIdx.x;
  int nbase = blockIdx.x * 16;
  for (int r = 0; r < NDIM; ++r) Ws[r * H + j] = Wn[r * H + j];
#pragma unroll
  for (int t = 0; t < 4; ++t) {
    int f = j + t * 128;
    xs[f] = x[nbase * NDIM + f];
  }
  __syncthreads();
  float b = bn[j];
  for (int nn = 0; nn < 16; ++nn) {
    float acc = b;
#pragma unroll
    for (int k = 0; k < NDIM; ++k)
      acc = fmaf(xs[nn * NDIM + k], Ws[k * H + j], acc);
    h[(size_t)(nbase + nn) * H + j] = acc;
  }
}

// ---------------- degree histogram over dst ----------------
__global__ __launch_bounds__(256) void degree_kernel(const int* __restrict__ ei,
                                                     int* __restrict__ deg) {
  int e = blockIdx.x * 256 + threadIdx.x;
  if (e < NE) atomicAdd(&deg[ei[NE + e]], 1);
}

// ---------------- precompute folded+split+transposed edge weights ----------------
// WtH/WtL : [l][128 n][272 k] bf16 hi/lo of Wm^T, where Wm rows 0..255 = mW1[0:256],
// rows 256..271 = We @ mW1[256:384].  bm = mb1 + be @ mW1[256:384].
__global__ __launch_bounds__(128) void precomp_wt_kernel(
    const float* __restrict__ mW1, const float* __restrict__ mb1,
    const float* __restrict__ We, const float* __restrict__ be,
    __bf16* __restrict__ WtH, __bf16* __restrict__ WtL, float* __restrict__ bm) {
  int l = blockIdx.x / 273;
  int r = blockIdx.x % 273;
  int n = threadIdx.x;
  const float* w1 = mW1 + (size_t)l * 384 * H;
  if (r < 272) {
    float w;
    if (r < 256) {
      w = w1[(size_t)r * H + n];
    } else {
      int i = r - 256;
      float s = 0.f;
      for (int c = 0; c < H; ++c)
        s = fmaf(We[i * H + c], w1[(size_t)(256 + c) * H + n], s);
      w = s;
    }
    __bf16 hi = (__bf16)w;
    __bf16 lo = (__bf16)(w - (float)hi);
    size_t idx = ((size_t)l * H + n) * KTOT + r;
    WtH[idx] = hi;
    WtL[idx] = lo;
  } else {
    float s = mb1[l * H + n];
    for (int c = 0; c < H; ++c)
      s = fmaf(be[c], w1[(size_t)(256 + c) * H + n], s);
    bm[l * H + n] = s;
  }
}

// ---------------- precompute folded update weights ----------------
__global__ __launch_bounds__(128) void precomp_wu_kernel(
    const float* __restrict__ uW1, const float* __restrict__ mW2,
    const float* __restrict__ mb2, float* __restrict__ Wu,
    float* __restrict__ va) {
  int l = blockIdx.x / 257;
  int r = blockIdx.x % 257;
  int j = threadIdx.x;
  const float* u1 = uW1 + (size_t)l * 256 * H;
  if (r < 128) {
    Wu[((size_t)l * 256 + r) * H + j] = u1[(size_t)r * H + j];
  } else if (r < 256) {
    int i = r - 128;
    const float* m2 = mW2 + ((size_t)l * H + i) * H;
    float s = 0.f;
    for (int c = 0; c < H; ++c)
      s = fmaf(m2[c], u1[(size_t)(128 + c) * H + j], s);
    Wu[((size_t)l * 256 + r) * H + j] = s;
  } else {
    float s = 0.f;
    for (int c = 0; c < H; ++c)
      s = fmaf(mb2[l * H + c], u1[(size_t)(128 + c) * H + j], s);
    va[l * H + j] = s;
  }
}

// ---------------- MFMA edge MLP + scatter-add of relu(hidden) ----------------
// 128 edges/block, 4 waves; wave = 32 edges x 128 cols via mfma_f32_32x32x16_bf16.
// fp32 accuracy via 3-term bf16 split: C = Ah*Bh + Al*Bh + Ah*Bl.
// A gathered per-lane from global (h rows / edge attrs); B (WtH/WtL) double-buffered
// through LDS in 16-k chunks. Epilogue: bias+relu, coalesced unsafeAtomicAdd from
// C-frags (lanes 0..31 = consecutive cols -> full 128B segments).
__global__ __launch_bounds__(256) void edge_mlp_kernel(
    const float* __restrict__ h, const int* __restrict__ ei,
    const float* __restrict__ ea, const __bf16* __restrict__ WtH,
    const __bf16* __restrict__ WtL, const float* __restrict__ bm,
    float* __restrict__ aggrH) {
  __shared__ __bf16 Bt[2][2][128][16];  // [dbuf][hi/lo][n][k16] = 16 KB
  __shared__ int dstS[EPB];
  int tid = threadIdx.x;
  int ebase = blockIdx.x * EPB;
  if (tid < EPB) dstS[tid] = ei[NE + ebase + tid];
  int wid = tid >> 6, lane = tid & 63;
  int m = lane & 31, half = lane >> 5;  // A row (edge) / k-octet selector
  int edge = ebase + wid * 32 + m;
  int srcN = ei[edge];
  // B staging: thread -> (row sn, 16B half sh)
  int sn = tid >> 1, sh = tid & 1;
  const __bf16* gH = WtH + (size_t)sn * KTOT + sh * 8;
  const __bf16* gL = WtL + (size_t)sn * KTOT + sh * 8;
  *(short8*)&Bt[0][0][sn][sh * 8] = *(const short8*)gH;
  *(short8*)&Bt[0][1][sn][sh * 8] = *(const short8*)gL;
  __syncthreads();  // Bt chunk 0 + dstS visible
  int dstN = dstS[wid * 32 + m];
  const float* aDst = h + (size_t)dstN * H + half * 8;
  const float* aSrc = h + (size_t)srcN * H + half * 8;
  const float* aEa = ea + (size_t)edge * EDIM + half * 8;

  f32x16 acc[4];
#pragma unroll
  for (int nt = 0; nt < 4; ++nt)
#pragma unroll
    for (int r = 0; r < 16; ++r) acc[nt][r] = 0.f;

  float4 a0 = *(const float4*)aDst;        // step 0: k 0..15 of h_dst
  float4 a1 = *(const float4*)(aDst + 4);

  for (int s = 0; s < 17; ++s) {
    int buf = s & 1;
    if (s < 16) {  // stage B chunk s+1 into other buffer
      int k0 = (s + 1) * 16;
      *(short8*)&Bt[buf ^ 1][0][sn][sh * 8] = *(const short8*)(gH + k0);
      *(short8*)&Bt[buf ^ 1][1][sn][sh * 8] = *(const short8*)(gL + k0);
    }
    float4 na0 = a0, na1 = a1;
    if (s < 16) {  // prefetch A for step s+1
      int sp = s + 1;
      const float* p = (sp < 8) ? (aDst + sp * 16)
                     : (sp < 16) ? (aSrc + (sp - 8) * 16) : aEa;
      na0 = *(const float4*)p;
      na1 = *(const float4*)(p + 4);
    }
    // split current A octet into bf16 hi/lo frags
    float af[8] = {a0.x, a0.y, a0.z, a0.w, a1.x, a1.y, a1.z, a1.w};
    bf16x8 ah, al;
#pragma unroll
    for (int j = 0; j < 8; ++j) {
      __bf16 hi = (__bf16)af[j];
      ah[j] = hi;
      al[j] = (__bf16)(af[j] - (float)hi);
    }
#pragma unroll
    for (int nt = 0; nt < 4; ++nt) {
      bf16x8 bh = *(bf16x8*)&Bt[buf][0][nt * 32 + m][half * 8];
      bf16x8 bl = *(bf16x8*)&Bt[buf][1][nt * 32 + m][half * 8];
      acc[nt] = __builtin_amdgcn_mfma_f32_32x32x16_bf16(ah, bh, acc[nt], 0, 0, 0);
      acc[nt] = __builtin_amdgcn_mfma_f32_32x32x16_bf16(al, bh, acc[nt], 0, 0, 0);
      acc[nt] = __builtin_amdgcn_mfma_f32_32x32x16_bf16(ah, bl, acc[nt], 0, 0, 0);
    }
    __syncthreads();
    a0 = na0;
    a1 = na1;
  }

  // epilogue: bias + relu + coalesced atomics from C layout
  // (col=lane&31, row=(r&3)+8*(r>>2)+4*half  -- HW-verified 32x32 C/D mapping)
  float bias[4];
#pragma unroll
  for (int nt = 0; nt < 4; ++nt) bias[nt] = bm[nt * 32 + m];
#pragma unroll
  for (int nt = 0; nt < 4; ++nt) {
#pragma unroll
    for (int r = 0; r < 16; ++r) {
      int row = (r & 3) + 8 * (r >> 2) + 4 * half;
      int el = wid * 32 + row;
      float v = fmaxf(acc[nt][r] + bias[nt], 0.f);
      unsafeAtomicAdd(&aggrH[(size_t)dstS[el] * H + nt * 32 + m], v);
    }
  }
}

// ---------------- fused node update ----------------
__global__ __launch_bounds__(256) void node_update_kernel(
    float* __restrict__ h, const float* __restrict__ aggrH,
    const int* __restrict__ deg, const float* __restrict__ Wu,
    const float* __restrict__ va, const float* __restrict__ ub1,
    const float* __restrict__ uW2, const float* __restrict__ ub2) {
  __shared__ float ins[16][256];  // [h(128) | aggrH(128)]
  __shared__ float ts[16][128];
  __shared__ float degS[16];
  int tid = threadIdx.x;
  int nbase = blockIdx.x * 16;
  if (tid < 16) degS[tid] = (float)deg[nbase + tid];
#pragma unroll
  for (int t = 0; t < 4; ++t) {
    int f = tid + t * 256;
    int r = f >> 5, c4 = f & 31;
    const float* s = (r < 16) ? (h + (size_t)(nbase + r) * H)
                              : (aggrH + (size_t)(nbase + r - 16) * H);
    float4 v = ((const float4*)s)[c4];
    float* q = (r < 16) ? &ins[r][c4 * 4] : &ins[r - 16][H + c4 * 4];
    *(float4*)q = v;
  }
  __syncthreads();
  int j = tid & 127;
  int n0 = (tid >> 7) * 8;
  float acc[8];
  {
    float b = ub1[j], vaj = va[j];
#pragma unroll
    for (int e = 0; e < 8; ++e) acc[e] = fmaf(degS[n0 + e], vaj, b);
  }
  for (int k = 0; k < 256; k += 4) {
    float w0 = Wu[(size_t)(k + 0) * H + j];
    float w1 = Wu[(size_t)(k + 1) * H + j];
    float w2 = Wu[(size_t)(k + 2) * H + j];
    float w3 = Wu[(size_t)(k + 3) * H + j];
#pragma unroll
    for (int e = 0; e < 8; ++e) {
      float4 v = *(const float4*)&ins[n0 + e][k];
      acc[e] = fmaf(v.x, w0, acc[e]);
      acc[e] = fmaf(v.y, w1, acc[e]);
      acc[e] = fmaf(v.z, w2, acc[e]);
      acc[e] = fmaf(v.w, w3, acc[e]);
    }
  }
#pragma unroll
  for (int e = 0; e < 8; ++e) ts[n0 + e][j] = fmaxf(acc[e], 0.f);
  __syncthreads();
  {
    float b2 = ub2[j];
#pragma unroll
    for (int e = 0; e < 8; ++e) acc[e] = b2;
  }
  for (int k = 0; k < 128; k += 4) {
    float w0 = uW2[(size_t)(k + 0) * H + j];
    float w1 = uW2[(size_t)(k + 1) * H + j];
    float w2 = uW2[(size_t)(k + 2) * H + j];
    float w3 = uW2[(size_t)(k + 3) * H + j];
#pragma unroll
    for (int e = 0; e < 8; ++e) {
      float4 v = *(const float4*)&ts[n0 + e][k];
      acc[e] = fmaf(v.x, w0, acc[e]);
      acc[e] = fmaf(v.y, w1, acc[e]);
      acc[e] = fmaf(v.z, w2, acc[e]);
      acc[e] = fmaf(v.w, w3, acc[e]);
    }
  }
#pragma unroll
  for (int e = 0; e < 8; ++e) {
    size_t idx = (size_t)(nbase + n0 + e) * H + j;
    h[idx] += acc[e];
  }
}

// ---------------- batch mean pooling (batch is sorted) ----------------
__global__ __launch_bounds__(128) void pool_kernel(
    const float* __restrict__ h, const int* __restrict__ batch,
    float* __restrict__ pooled, int* __restrict__ counts) {
  int j = threadIdx.x;
  int nbase = blockIdx.x * 128;
  int nend = nbase + 128;
  if (nend > NN) nend = NN;
  int cur = batch[nbase];
  float sum = 0.f;
  int cnt = 0;
  for (int n = nbase; n < nend; ++n) {
    int b = batch[n];
    if (b != cur) {
      unsafeAtomicAdd(&pooled[cur * H + j], sum);
      if (j == 0) atomicAdd(&counts[cur], cnt);
      sum = 0.f; cnt = 0; cur = b;
    }
    sum += h[(size_t)n * H + j];
    cnt++;
  }
  unsafeAtomicAdd(&pooled[cur * H + j], sum);
  if (j == 0) atomicAdd(&counts[cur], cnt);
}

// ---------------- readout MLP ----------------
__global__ __launch_bounds__(128) void readout_kernel(
    const float* __restrict__ pooled, const int* __restrict__ counts,
    const float* __restrict__ gf, const float* __restrict__ Wg,
    const float* __restrict__ bg, const float* __restrict__ rW1,
    const float* __restrict__ rb1, const float* __restrict__ rW2,
    const float* __restrict__ rb2, const float* __restrict__ rW3,
    const float* __restrict__ rb3, float* __restrict__ out) {
  __shared__ float fin[256];
  __shared__ float t1[128];
  __shared__ float t2[64];
  int j = threadIdx.x;
  for (int b = 0; b < NBATCH; ++b) {
    float cnt = (float)counts[b];
    if (cnt < 1.f) cnt = 1.f;
    fin[j] = pooled[b * H + j] / cnt;
    fin[H + j] = fmaf(gf[b], Wg[j], bg[j]);
    __syncthreads();
    float a = rb1[j];
    for (int k = 0; k < 256; ++k) a = fmaf(fin[k], rW1[k * H + j], a);
    t1[j] = fmaxf(a, 0.f);
    __syncthreads();
    if (j < 64) {
      float a2 = rb2[j];
      for (int k = 0; k < 128; ++k) a2 = fmaf(t1[k], rW2[k * 64 + j], a2);
      t2[j] = fmaxf(a2, 0.f);
    }
    __syncthreads();
    if (j < 64) {
      float p = t2[j] * rW3[j];
#pragma unroll
      for (int off = 32; off; off >>= 1) p += __shfl_down(p, off);
      if (j == 0) out[b] = p + rb3[0];
    }
    __syncthreads();
  }
}

extern "C" void kernel_launch(void* const* d_in, const int* in_sizes, int n_in,
                              void* d_out, int out_size, void* d_ws, size_t ws_size,
                              hipStream_t stream) {
  const float* x   = (const float*)d_in[0];
  const float* ea  = (const float*)d_in[1];
  const float* gf  = (const float*)d_in[2];
  const int*   ei  = (const int*)d_in[3];
  const int*   bat = (const int*)d_in[4];
  const float* Wn  = (const float*)d_in[5];
  const float* bn  = (const float*)d_in[6];
  const float* We  = (const float*)d_in[7];
  const float* be  = (const float*)d_in[8];
  const float* Wg  = (const float*)d_in[9];
  const float* bg  = (const float*)d_in[10];
  const float* mW1 = (const float*)d_in[11];
  const float* mb1 = (const float*)d_in[12];
  const float* mW2 = (const float*)d_in[13];
  const float* mb2 = (const float*)d_in[14];
  const float* uW1 = (const float*)d_in[15];
  const float* ub1 = (const float*)d_in[16];
  const float* uW2 = (const float*)d_in[17];
  const float* ub2 = (const float*)d_in[18];
  const float* rW1 = (const float*)d_in[19];
  const float* rb1 = (const float*)d_in[20];
  const float* rW2 = (const float*)d_in[21];
  const float* rb2 = (const float*)d_in[22];
  const float* rW3 = (const float*)d_in[23];
  const float* rb3 = (const float*)d_in[24];

  char* p = (char*)d_ws;
  float*  h     = (float*)p;  p += (size_t)NN * H * 4;         // 25.6 MB
  float*  aggrH = (float*)p;  p += (size_t)NN * H * 4;         // 25.6 MB
  __bf16* WtH   = (__bf16*)p; p += (size_t)NLAYERS * H * KTOT * 2;  // 209 KB
  __bf16* WtL   = (__bf16*)p; p += (size_t)NLAYERS * H * KTOT * 2;  // 209 KB
  float*  bm    = (float*)p;  p += (size_t)NLAYERS * H * 4;
  float*  Wu    = (float*)p;  p += (size_t)NLAYERS * 256 * H * 4;
  float*  va    = (float*)p;  p += (size_t)NLAYERS * H * 4;
  int*    deg   = (int*)p;    p += (size_t)NN * 4;
  float*  pooled= (float*)p;  p += (size_t)NBATCH * H * 4;
  int*    counts= (int*)p;    p += 64;

  hipMemsetAsync(deg, 0, (size_t)NN * 4, stream);
  hipMemsetAsync(pooled, 0, (size_t)NBATCH * H * 4, stream);
  hipMemsetAsync(counts, 0, 64, stream);

  embed_nodes_kernel<<<NN / 16, 128, 0, stream>>>(x, Wn, bn, h);
  degree_kernel<<<(NE + 255) / 256, 256, 0, stream>>>(ei, deg);
  precomp_wt_kernel<<<NLAYERS * 273, 128, 0, stream>>>(mW1, mb1, We, be, WtH, WtL, bm);
  precomp_wu_kernel<<<NLAYERS * 257, 128, 0, stream>>>(uW1, mW2, mb2, Wu, va);

  for (int l = 0; l < NLAYERS; ++l) {
    hipMemsetAsync(aggrH, 0, (size_t)NN * H * 4, stream);
    edge_mlp_kernel<<<NE / EPB, 256, 0, stream>>>(
        h, ei, ea, WtH + (size_t)l * H * KTOT, WtL + (size_t)l * H * KTOT,
        bm + (size_t)l * H, aggrH);
    node_update_kernel<<<NN / 16, 256, 0, stream>>>(
        h, aggrH, deg, Wu + (size_t)l * 256 * H, va + (size_t)l * H,
        ub1 + (size_t)l * H, uW2 + (size_t)l * H * H, ub2 + (size_t)l * H);
  }

  pool_kernel<<<(NN + 127) / 128, 128, 0, stream>>>(h, bat, pooled, counts);
  readout_kernel<<<1, 128, 0, stream>>>(pooled, counts, gf, Wg, bg, rW1, rb1,
                                        rW2, rb2, rW3, rb3, (float*)d_out);
}

// Round 5
// 1194.304 us; speedup vs baseline: 2.3933x; 1.0249x over previous
//
#include <hip/hip_runtime.h>

#define NN 50000
#define NE 400000
#define NBATCH 8
#define NDIM 32
#define EDIM 16
#define H 128
#define NLAYERS 3
#define EPB 128   // edges per block in edge_mlp (4 waves x 32 edges)
#define KTOT 272  // folded K: 128 dst + 128 src + 16 edge-attr
#define NCHUNK 17 // K chunks of 16
#define CHUNK_ELEMS 4096  // 2 hilo * 4 nt * 64 lane * 8 = bf16 elems per chunk

typedef __attribute__((ext_vector_type(8))) __bf16 bf16x8;
typedef __attribute__((ext_vector_type(16))) float f32x16;
typedef __attribute__((ext_vector_type(8))) short short8;

// ---------------- node embedding: h = x @ Wn + bn ----------------
__global__ __launch_bounds__(128) void embed_nodes_kernel(
    const float* __restrict__ x, const float* __restrict__ Wn,
    const float* __restrict__ bn, float* __restrict__ h) {
  __shared__ float Ws[NDIM * H];
  __shared__ float xs[16 * NDIM];
  int j = threadIdx.x;
  int nbase = blockIdx.x * 16;
  for (int r = 0; r < NDIM; ++r) Ws[r * H + j] = Wn[r * H + j];
#pragma unroll
  for (int t = 0; t < 4; ++t) {
    int f = j + t * 128;
    xs[f] = x[nbase * NDIM + f];
  }
  __syncthreads();
  float b = bn[j];
  for (int nn = 0; nn < 16; ++nn) {
    float acc = b;
#pragma unroll
    for (int k = 0; k < NDIM; ++k)
      acc = fmaf(xs[nn * NDIM + k], Ws[k * H + j], acc);
    h[(size_t)(nbase + nn) * H + j] = acc;
  }
}

// ---------------- degree histogram over dst ----------------
__global__ __launch_bounds__(256) void degree_kernel(const int* __restrict__ ei,
                                                     int* __restrict__ deg) {
  int e = blockIdx.x * 256 + threadIdx.x;
  if (e < NE) atomicAdd(&deg[ei[NE + e]], 1);
}

// ---------------- precompute folded+split edge weights, MFMA-frag-swizzled ----------------
// WtS[l][chunk][hilo][nt][lane][8] bf16, where logical Wt[n][k] = folded W^T:
//   k<256: mW1[l][k][n]; k in 256..271: (We @ mW1[l][256:384])[k-256][n]
//   n = nt*32 + (lane&31), k = chunk*16 + (lane>>5)*8 + j
// bm = mb1 + be @ mW1[256:384].
__global__ __launch_bounds__(256) void precomp_wt_kernel(
    const float* __restrict__ mW1, const float* __restrict__ mb1,
    const float* __restrict__ We, const float* __restrict__ be,
    __bf16* __restrict__ WtS, float* __restrict__ bm) {
  int l = blockIdx.x / 18;
  int c = blockIdx.x % 18;
  int tid = threadIdx.x;
  const float* w1 = mW1 + (size_t)l * 384 * H;
  if (c == 17) {
    if (tid < 128) {
      float s = mb1[l * H + tid];
      for (int q = 0; q < 128; ++q)
        s = fmaf(be[q], w1[(size_t)(256 + q) * H + tid], s);
      bm[l * H + tid] = s;
    }
    return;
  }
  int nt = tid >> 6, lane = tid & 63;
  int n = nt * 32 + (lane & 31);
  int half = lane >> 5;
  __bf16* dst = WtS + ((size_t)l * NCHUNK + c) * CHUNK_ELEMS;
#pragma unroll
  for (int j = 0; j < 8; ++j) {
    int k = c * 16 + half * 8 + j;
    float w;
    if (k < 256) {
      w = w1[(size_t)k * H + n];
    } else {
      int i = k - 256;
      float s = 0.f;
      for (int q = 0; q < 128; ++q)
        s = fmaf(We[i * H + q], w1[(size_t)(256 + q) * H + n], s);
      w = s;
    }
    __bf16 hi = (__bf16)w;
    __bf16 lo = (__bf16)(w - (float)hi);
    dst[((0 * 4 + nt) * 64 + lane) * 8 + j] = hi;
    dst[((1 * 4 + nt) * 64 + lane) * 8 + j] = lo;
  }
}

// ---------------- precompute folded update weights ----------------
__global__ __launch_bounds__(128) void precomp_wu_kernel(
    const float* __restrict__ uW1, const float* __restrict__ mW2,
    const float* __restrict__ mb2, float* __restrict__ Wu,
    float* __restrict__ va) {
  int l = blockIdx.x / 257;
  int r = blockIdx.x % 257;
  int j = threadIdx.x;
  const float* u1 = uW1 + (size_t)l * 256 * H;
  if (r < 128) {
    Wu[((size_t)l * 256 + r) * H + j] = u1[(size_t)r * H + j];
  } else if (r < 256) {
    int i = r - 128;
    const float* m2 = mW2 + ((size_t)l * H + i) * H;
    float s = 0.f;
    for (int c = 0; c < H; ++c)
      s = fmaf(m2[c], u1[(size_t)(128 + c) * H + j], s);
    Wu[((size_t)l * 256 + r) * H + j] = s;
  } else {
    float s = 0.f;
    for (int c = 0; c < H; ++c)
      s = fmaf(mb2[l * H + c], u1[(size_t)(128 + c) * H + j], s);
    va[l * H + j] = s;
  }
}

// ---------------- MFMA edge MLP + scatter-add of relu(hidden) ----------------
// 128 edges/block, 4 waves; wave = 32 edges x 128 cols via mfma_f32_32x32x16_bf16.
// fp32 accuracy via 3-term bf16 split: C = Ah*Bh + Al*Bh + Ah*Bl.
// A gathered per-lane from global; B pre-swizzled to per-lane fragment order, so
// LDS staging is a flat coalesced copy and frag reads are base+lane*16B
// (conflict-free). Epilogue: bias+relu, coalesced unsafeAtomicAdd from C-frags.
__global__ __launch_bounds__(256) void edge_mlp_kernel(
    const float* __restrict__ h, const int* __restrict__ ei,
    const float* __restrict__ ea, const __bf16* __restrict__ WtS,
    const float* __restrict__ bm, float* __restrict__ aggrH) {
  __shared__ __bf16 Bt[2][CHUNK_ELEMS];  // dbuf x 8KB
  __shared__ int dstS[EPB];
  int tid = threadIdx.x;
  int ebase = blockIdx.x * EPB;
  if (tid < EPB) dstS[tid] = ei[NE + ebase + tid];
  int wid = tid >> 6, lane = tid & 63;
  int m = lane & 31, half = lane >> 5;
  int edge = ebase + wid * 32 + m;
  int srcN = ei[edge];
  // B staging: flat copy, thread -> 2 x 16B slots
  const short8* gW = (const short8*)WtS;  // 512 short8 per chunk
  short8* sB0 = (short8*)&Bt[0][0];
  short8* sB1 = (short8*)&Bt[1][0];
  sB0[tid] = gW[tid];
  sB0[tid + 256] = gW[tid + 256];
  __syncthreads();  // Bt chunk 0 + dstS visible
  int dstN = dstS[wid * 32 + m];
  const float* aDst = h + (size_t)dstN * H + half * 8;
  const float* aSrc = h + (size_t)srcN * H + half * 8;
  const float* aEa = ea + (size_t)edge * EDIM + half * 8;

  f32x16 acc[4];
#pragma unroll
  for (int nt = 0; nt < 4; ++nt)
#pragma unroll
    for (int r = 0; r < 16; ++r) acc[nt][r] = 0.f;

  float4 a0 = *(const float4*)aDst;  // step 0: k 0..15 of h_dst
  float4 a1 = *(const float4*)(aDst + 4);

  for (int s = 0; s < NCHUNK; ++s) {
    int buf = s & 1;
    if (s < NCHUNK - 1) {  // stage B chunk s+1 into other buffer
      const short8* g = gW + (size_t)(s + 1) * 512;
      short8* sb = buf ? sB0 : sB1;
      sb[tid] = g[tid];
      sb[tid + 256] = g[tid + 256];
    }
    float4 na0 = a0, na1 = a1;
    if (s < NCHUNK - 1) {  // prefetch A for step s+1
      int sp = s + 1;
      const float* p = (sp < 8) ? (aDst + sp * 16)
                     : (sp < 16) ? (aSrc + (sp - 8) * 16) : aEa;
      na0 = *(const float4*)p;
      na1 = *(const float4*)(p + 4);
    }
    // split current A octet into bf16 hi/lo frags
    float af[8] = {a0.x, a0.y, a0.z, a0.w, a1.x, a1.y, a1.z, a1.w};
    bf16x8 ah, al;
#pragma unroll
    for (int j = 0; j < 8; ++j) {
      __bf16 hi = (__bf16)af[j];
      ah[j] = hi;
      al[j] = (__bf16)(af[j] - (float)hi);
    }
    const __bf16* bb = &Bt[buf][0];
#pragma unroll
    for (int nt = 0; nt < 4; ++nt) {
      bf16x8 bh = *(const bf16x8*)&bb[((0 * 4 + nt) * 64 + lane) * 8];
      bf16x8 bl = *(const bf16x8*)&bb[((1 * 4 + nt) * 64 + lane) * 8];
      acc[nt] = __builtin_amdgcn_mfma_f32_32x32x16_bf16(ah, bh, acc[nt], 0, 0, 0);
      acc[nt] = __builtin_amdgcn_mfma_f32_32x32x16_bf16(al, bh, acc[nt], 0, 0, 0);
      acc[nt] = __builtin_amdgcn_mfma_f32_32x32x16_bf16(ah, bl, acc[nt], 0, 0, 0);
    }
    __syncthreads();
    a0 = na0;
    a1 = na1;
  }

  // epilogue: bias + relu + coalesced atomics from C layout
  // (col=lane&31, row=(r&3)+8*(r>>2)+4*half -- HW-verified 32x32 C/D mapping)
  float bias[4];
#pragma unroll
  for (int nt = 0; nt < 4; ++nt) bias[nt] = bm[nt * 32 + m];
#pragma unroll
  for (int nt = 0; nt < 4; ++nt) {
#pragma unroll
    for (int r = 0; r < 16; ++r) {
      int row = (r & 3) + 8 * (r >> 2) + 4 * half;
      int el = wid * 32 + row;
      float v = fmaxf(acc[nt][r] + bias[nt], 0.f);
      unsafeAtomicAdd(&aggrH[(size_t)dstS[el] * H + nt * 32 + m], v);
    }
  }
}

// ---------------- fused node update ----------------
__global__ __launch_bounds__(256) void node_update_kernel(
    float* __restrict__ h, const float* __restrict__ aggrH,
    const int* __restrict__ deg, const float* __restrict__ Wu,
    const float* __restrict__ va, const float* __restrict__ ub1,
    const float* __restrict__ uW2, const float* __restrict__ ub2) {
  __shared__ float ins[16][256];  // [h(128) | aggrH(128)]
  __shared__ float ts[16][128];
  __shared__ float degS[16];
  int tid = threadIdx.x;
  int nbase = blockIdx.x * 16;
  if (tid < 16) degS[tid] = (float)deg[nbase + tid];
#pragma unroll
  for (int t = 0; t < 4; ++t) {
    int f = tid + t * 256;
    int r = f >> 5, c4 = f & 31;
    const float* s = (r < 16) ? (h + (size_t)(nbase + r) * H)
                              : (aggrH + (size_t)(nbase + r - 16) * H);
    float4 v = ((const float4*)s)[c4];
    float* q = (r < 16) ? &ins[r][c4 * 4] : &ins[r - 16][H + c4 * 4];
    *(float4*)q = v;
  }
  __syncthreads();
  int j = tid & 127;
  int n0 = (tid >> 7) * 8;
  float acc[8];
  {
    float b = ub1[j], vaj = va[j];
#pragma unroll
    for (int e = 0; e < 8; ++e) acc[e] = fmaf(degS[n0 + e], vaj, b);
  }
  for (int k = 0; k < 256; k += 4) {
    float w0 = Wu[(size_t)(k + 0) * H + j];
    float w1 = Wu[(size_t)(k + 1) * H + j];
    float w2 = Wu[(size_t)(k + 2) * H + j];
    float w3 = Wu[(size_t)(k + 3) * H + j];
#pragma unroll
    for (int e = 0; e < 8; ++e) {
      float4 v = *(const float4*)&ins[n0 + e][k];
      acc[e] = fmaf(v.x, w0, acc[e]);
      acc[e] = fmaf(v.y, w1, acc[e]);
      acc[e] = fmaf(v.z, w2, acc[e]);
      acc[e] = fmaf(v.w, w3, acc[e]);
    }
  }
#pragma unroll
  for (int e = 0; e < 8; ++e) ts[n0 + e][j] = fmaxf(acc[e], 0.f);
  __syncthreads();
  {
    float b2 = ub2[j];
#pragma unroll
    for (int e = 0; e < 8; ++e) acc[e] = b2;
  }
  for (int k = 0; k < 128; k += 4) {
    float w0 = uW2[(size_t)(k + 0) * H + j];
    float w1 = uW2[(size_t)(k + 1) * H + j];
    float w2 = uW2[(size_t)(k + 2) * H + j];
    float w3 = uW2[(size_t)(k + 3) * H + j];
#pragma unroll
    for (int e = 0; e < 8; ++e) {
      float4 v = *(const float4*)&ts[n0 + e][k];
      acc[e] = fmaf(v.x, w0, acc[e]);
      acc[e] = fmaf(v.y, w1, acc[e]);
      acc[e] = fmaf(v.z, w2, acc[e]);
      acc[e] = fmaf(v.w, w3, acc[e]);
    }
  }
#pragma unroll
  for (int e = 0; e < 8; ++e) {
    size_t idx = (size_t)(nbase + n0 + e) * H + j;
    h[idx] += acc[e];
  }
}

// ---------------- batch mean pooling (batch is sorted) ----------------
__global__ __launch_bounds__(128) void pool_kernel(
    const float* __restrict__ h, const int* __restrict__ batch,
    float* __restrict__ pooled, int* __restrict__ counts) {
  int j = threadIdx.x;
  int nbase = blockIdx.x * 128;
  int nend = nbase + 128;
  if (nend > NN) nend = NN;
  int cur = batch[nbase];
  float sum = 0.f;
  int cnt = 0;
  for (int n = nbase; n < nend; ++n) {
    int b = batch[n];
    if (b != cur) {
      unsafeAtomicAdd(&pooled[cur * H + j], sum);
      if (j == 0) atomicAdd(&counts[cur], cnt);
      sum = 0.f; cnt = 0; cur = b;
    }
    sum += h[(size_t)n * H + j];
    cnt++;
  }
  unsafeAtomicAdd(&pooled[cur * H + j], sum);
  if (j == 0) atomicAdd(&counts[cur], cnt);
}

// ---------------- readout MLP ----------------
__global__ __launch_bounds__(128) void readout_kernel(
    const float* __restrict__ pooled, const int* __restrict__ counts,
    const float* __restrict__ gf, const float* __restrict__ Wg,
    const float* __restrict__ bg, const float* __restrict__ rW1,
    const float* __restrict__ rb1, const float* __restrict__ rW2,
    const float* __restrict__ rb2, const float* __restrict__ rW3,
    const float* __restrict__ rb3, float* __restrict__ out) {
  __shared__ float fin[256];
  __shared__ float t1[128];
  __shared__ float t2[64];
  int j = threadIdx.x;
  for (int b = 0; b < NBATCH; ++b) {
    float cnt = (float)counts[b];
    if (cnt < 1.f) cnt = 1.f;
    fin[j] = pooled[b * H + j] / cnt;
    fin[H + j] = fmaf(gf[b], Wg[j], bg[j]);
    __syncthreads();
    float a = rb1[j];
    for (int k = 0; k < 256; ++k) a = fmaf(fin[k], rW1[k * H + j], a);
    t1[j] = fmaxf(a, 0.f);
    __syncthreads();
    if (j < 64) {
      float a2 = rb2[j];
      for (int k = 0; k < 128; ++k) a2 = fmaf(t1[k], rW2[k * 64 + j], a2);
      t2[j] = fmaxf(a2, 0.f);
    }
    __syncthreads();
    if (j < 64) {
      float p = t2[j] * rW3[j];
#pragma unroll
      for (int off = 32; off; off >>= 1) p += __shfl_down(p, off);
      if (j == 0) out[b] = p + rb3[0];
    }
    __syncthreads();
  }
}

extern "C" void kernel_launch(void* const* d_in, const int* in_sizes, int n_in,
                              void* d_out, int out_size, void* d_ws, size_t ws_size,
                              hipStream_t stream) {
  const float* x   = (const float*)d_in[0];
  const float* ea  = (const float*)d_in[1];
  const float* gf  = (const float*)d_in[2];
  const int*   ei  = (const int*)d_in[3];
  const int*   bat = (const int*)d_in[4];
  const float* Wn  = (const float*)d_in[5];
  const float* bn  = (const float*)d_in[6];
  const float* We  = (const float*)d_in[7];
  const float* be  = (const float*)d_in[8];
  const float* Wg  = (const float*)d_in[9];
  const float* bg  = (const float*)d_in[10];
  const float* mW1 = (const float*)d_in[11];
  const float* mb1 = (const float*)d_in[12];
  const float* mW2 = (const float*)d_in[13];
  const float* mb2 = (const float*)d_in[14];
  const float* uW1 = (const float*)d_in[15];
  const float* ub1 = (const float*)d_in[16];
  const float* uW2 = (const float*)d_in[17];
  const float* ub2 = (const float*)d_in[18];
  const float* rW1 = (const float*)d_in[19];
  const float* rb1 = (const float*)d_in[20];
  const float* rW2 = (const float*)d_in[21];
  const float* rb2 = (const float*)d_in[22];
  const float* rW3 = (const float*)d_in[23];
  const float* rb3 = (const float*)d_in[24];

  char* p = (char*)d_ws;
  float*  h     = (float*)p;  p += (size_t)NN * H * 4;         // 25.6 MB
  float*  aggrH = (float*)p;  p += (size_t)NN * H * 4;         // 25.6 MB
  __bf16* WtS   = (__bf16*)p; p += (size_t)NLAYERS * NCHUNK * CHUNK_ELEMS * 2;  // 418 KB
  float*  bm    = (float*)p;  p += (size_t)NLAYERS * H * 4;
  float*  Wu    = (float*)p;  p += (size_t)NLAYERS * 256 * H * 4;
  float*  va    = (float*)p;  p += (size_t)NLAYERS * H * 4;
  int*    deg   = (int*)p;    p += (size_t)NN * 4;
  float*  pooled= (float*)p;  p += (size_t)NBATCH * H * 4;
  int*    counts= (int*)p;    p += 64;

  hipMemsetAsync(deg, 0, (size_t)NN * 4, stream);
  hipMemsetAsync(pooled, 0, (size_t)NBATCH * H * 4, stream);
  hipMemsetAsync(counts, 0, 64, stream);

  embed_nodes_kernel<<<NN / 16, 128, 0, stream>>>(x, Wn, bn, h);
  degree_kernel<<<(NE + 255) / 256, 256, 0, stream>>>(ei, deg);
  precomp_wt_kernel<<<NLAYERS * 18, 256, 0, stream>>>(mW1, mb1, We, be, WtS, bm);
  precomp_wu_kernel<<<NLAYERS * 257, 128, 0, stream>>>(uW1, mW2, mb2, Wu, va);

  for (int l = 0; l < NLAYERS; ++l) {
    hipMemsetAsync(aggrH, 0, (size_t)NN * H * 4, stream);
    edge_mlp_kernel<<<NE / EPB, 256, 0, stream>>>(
        h, ei, ea, WtS + (size_t)l * NCHUNK * CHUNK_ELEMS,
        bm + (size_t)l * H, aggrH);
    node_update_kernel<<<NN / 16, 256, 0, stream>>>(
        h, aggrH, deg, Wu + (size_t)l * 256 * H, va + (size_t)l * H,
        ub1 + (size_t)l * H, uW2 + (size_t)l * H * H, ub2 + (size_t)l * H);
  }

  pool_kernel<<<(NN + 127) / 128, 128, 0, stream>>>(h, bat, pooled, counts);
  readout_kernel<<<1, 128, 0, stream>>>(pooled, counts, gf, Wg, bg, rW1, rb1,
                                        rW2, rb2, rW3, rb3, (float*)d_out);
}

// Round 6
// 1164.356 us; speedup vs baseline: 2.4549x; 1.0257x over previous
//
#include <hip/hip_runtime.h>

#define NN 50000
#define NE 400000
#define NBATCH 8
#define NDIM 32
#define EDIM 16
#define H 128
#define NLAYERS 3
#define EPB 128   // edges per block in edge_mlp (4 waves x 32 edges)
#define KTOT 272  // folded K: 128 dst + 128 src + 16 edge-attr
#define NCHUNK 17 // K chunks of 16
#define CHUNK_ELEMS 4096  // 2 hilo * 4 nt * 64 lane * 8 = bf16 elems per chunk

typedef __attribute__((ext_vector_type(8))) __bf16 bf16x8;
typedef __attribute__((ext_vector_type(16))) float f32x16;
typedef __attribute__((ext_vector_type(8))) short short8;

// barrier that drains LDS only -- leaves global loads in flight
// (HIP __syncthreads emits s_waitcnt vmcnt(0) which defeats the prefetch pipeline)
__device__ __forceinline__ void block_sync_lds() {
  asm volatile("s_waitcnt lgkmcnt(0)\ns_barrier" ::: "memory");
}

// ---------------- node embedding: h = x @ Wn + bn ----------------
__global__ __launch_bounds__(128) void embed_nodes_kernel(
    const float* __restrict__ x, const float* __restrict__ Wn,
    const float* __restrict__ bn, float* __restrict__ h) {
  __shared__ float Ws[NDIM * H];
  __shared__ float xs[16 * NDIM];
  int j = threadIdx.x;
  int nbase = blockIdx.x * 16;
  for (int r = 0; r < NDIM; ++r) Ws[r * H + j] = Wn[r * H + j];
#pragma unroll
  for (int t = 0; t < 4; ++t) {
    int f = j + t * 128;
    xs[f] = x[nbase * NDIM + f];
  }
  __syncthreads();
  float b = bn[j];
  for (int nn = 0; nn < 16; ++nn) {
    float acc = b;
#pragma unroll
    for (int k = 0; k < NDIM; ++k)
      acc = fmaf(xs[nn * NDIM + k], Ws[k * H + j], acc);
    h[(size_t)(nbase + nn) * H + j] = acc;
  }
}

// ---------------- degree histogram over dst ----------------
__global__ __launch_bounds__(256) void degree_kernel(const int* __restrict__ ei,
                                                     int* __restrict__ deg) {
  int e = blockIdx.x * 256 + threadIdx.x;
  if (e < NE) atomicAdd(&deg[ei[NE + e]], 1);
}

// ---------------- precompute folded+split edge weights, MFMA-frag-swizzled ----------------
__global__ __launch_bounds__(256) void precomp_wt_kernel(
    const float* __restrict__ mW1, const float* __restrict__ mb1,
    const float* __restrict__ We, const float* __restrict__ be,
    __bf16* __restrict__ WtS, float* __restrict__ bm) {
  int l = blockIdx.x / 18;
  int c = blockIdx.x % 18;
  int tid = threadIdx.x;
  const float* w1 = mW1 + (size_t)l * 384 * H;
  if (c == 17) {
    if (tid < 128) {
      float s = mb1[l * H + tid];
      for (int q = 0; q < 128; ++q)
        s = fmaf(be[q], w1[(size_t)(256 + q) * H + tid], s);
      bm[l * H + tid] = s;
    }
    return;
  }
  int nt = tid >> 6, lane = tid & 63;
  int n = nt * 32 + (lane & 31);
  int half = lane >> 5;
  __bf16* dst = WtS + ((size_t)l * NCHUNK + c) * CHUNK_ELEMS;
#pragma unroll
  for (int j = 0; j < 8; ++j) {
    int k = c * 16 + half * 8 + j;
    float w;
    if (k < 256) {
      w = w1[(size_t)k * H + n];
    } else {
      int i = k - 256;
      float s = 0.f;
      for (int q = 0; q < 128; ++q)
        s = fmaf(We[i * H + q], w1[(size_t)(256 + q) * H + n], s);
      w = s;
    }
    __bf16 hi = (__bf16)w;
    __bf16 lo = (__bf16)(w - (float)hi);
    dst[((0 * 4 + nt) * 64 + lane) * 8 + j] = hi;
    dst[((1 * 4 + nt) * 64 + lane) * 8 + j] = lo;
  }
}

// ---------------- precompute folded update weights ----------------
__global__ __launch_bounds__(128) void precomp_wu_kernel(
    const float* __restrict__ uW1, const float* __restrict__ mW2,
    const float* __restrict__ mb2, float* __restrict__ Wu,
    float* __restrict__ va) {
  int l = blockIdx.x / 257;
  int r = blockIdx.x % 257;
  int j = threadIdx.x;
  const float* u1 = uW1 + (size_t)l * 256 * H;
  if (r < 128) {
    Wu[((size_t)l * 256 + r) * H + j] = u1[(size_t)r * H + j];
  } else if (r < 256) {
    int i = r - 128;
    const float* m2 = mW2 + ((size_t)l * H + i) * H;
    float s = 0.f;
    for (int c = 0; c < H; ++c)
      s = fmaf(m2[c], u1[(size_t)(128 + c) * H + j], s);
    Wu[((size_t)l * 256 + r) * H + j] = s;
  } else {
    float s = 0.f;
    for (int c = 0; c < H; ++c)
      s = fmaf(mb2[l * H + c], u1[(size_t)(128 + c) * H + j], s);
    va[l * H + j] = s;
  }
}

// ---------------- MFMA edge MLP + scatter-add of relu(hidden) ----------------
// 128 edges/block, 4 waves; wave = 32 edges x 128 cols via mfma_f32_32x32x16_bf16.
// fp32 accuracy via 3-term bf16 split: C = Ah*Bh + Al*Bh + Ah*Bl.
// Software pipeline: chunk s+2 global->reg, chunk s+1 reg->LDS (buf^1),
// chunk s LDS->MFMA, with an lgkm-only barrier per step (global loads stay
// in flight across barriers -- AITER/CK style).
__global__ __launch_bounds__(256) void edge_mlp_kernel(
    const float* __restrict__ h, const int* __restrict__ ei,
    const float* __restrict__ ea, const __bf16* __restrict__ WtS,
    const float* __restrict__ bm, float* __restrict__ aggrH) {
  __shared__ __bf16 Bt[2][CHUNK_ELEMS];  // dbuf x 8KB
  __shared__ int dstS[EPB];
  int tid = threadIdx.x;
  int ebase = blockIdx.x * EPB;
  if (tid < EPB) dstS[tid] = ei[NE + ebase + tid];
  int wid = tid >> 6, lane = tid & 63;
  int m = lane & 31, half = lane >> 5;
  int edge = ebase + wid * 32 + m;
  int srcN = ei[edge];
  const short8* gW = (const short8*)WtS;  // 512 short8 per chunk
  short8* sB0 = (short8*)&Bt[0][0];
  short8* sB1 = (short8*)&Bt[1][0];
  // chunk 0 -> LDS buf0 (direct), chunk 1 -> regs
  {
    short8 c00 = gW[tid], c01 = gW[tid + 256];
    sB0[tid] = c00;
    sB0[tid + 256] = c01;
  }
  short8 p0 = gW[512 + tid], p1 = gW[512 + tid + 256];
  block_sync_lds();  // Bt chunk 0 + dstS visible
  int dstN = dstS[wid * 32 + m];
  const float* aDst = h + (size_t)dstN * H + half * 8;
  const float* aSrc = h + (size_t)srcN * H + half * 8;
  const float* aEa = ea + (size_t)edge * EDIM + half * 8;

  f32x16 acc[4];
#pragma unroll
  for (int nt = 0; nt < 4; ++nt)
#pragma unroll
    for (int r = 0; r < 16; ++r) acc[nt][r] = 0.f;

  float4 a0 = *(const float4*)aDst;  // step 0: k 0..15 of h_dst
  float4 a1 = *(const float4*)(aDst + 4);

  for (int s = 0; s < NCHUNK; ++s) {
    int buf = s & 1;
    // A prefetch for step s+1 (issued early; consumed next step)
    float4 na0 = a0, na1 = a1;
    if (s + 1 < NCHUNK) {
      int sp = s + 1;
      const float* pp = (sp < 8) ? (aDst + sp * 16)
                      : (sp < 16) ? (aSrc + (sp - 8) * 16) : aEa;
      na0 = *(const float4*)pp;
      na1 = *(const float4*)(pp + 4);
    }
    // stage chunk s+1 (regs, loaded at step s-1) into LDS buf^1,
    // then launch global loads for chunk s+2 into the same regs
    if (s + 1 < NCHUNK) {
      short8* sb = buf ? sB0 : sB1;
      sb[tid] = p0;
      sb[tid + 256] = p1;
      if (s + 2 < NCHUNK) {
        p0 = gW[(size_t)(s + 2) * 512 + tid];
        p1 = gW[(size_t)(s + 2) * 512 + tid + 256];
      }
    }
    // split current A octet into bf16 hi/lo frags
    float af[8] = {a0.x, a0.y, a0.z, a0.w, a1.x, a1.y, a1.z, a1.w};
    bf16x8 ah, al;
#pragma unroll
    for (int j = 0; j < 8; ++j) {
      __bf16 hi = (__bf16)af[j];
      ah[j] = hi;
      al[j] = (__bf16)(af[j] - (float)hi);
    }
    const __bf16* bb = &Bt[buf][0];
#pragma unroll
    for (int nt = 0; nt < 4; ++nt) {
      bf16x8 bh = *(const bf16x8*)&bb[((0 * 4 + nt) * 64 + lane) * 8];
      bf16x8 bl = *(const bf16x8*)&bb[((1 * 4 + nt) * 64 + lane) * 8];
      acc[nt] = __builtin_amdgcn_mfma_f32_32x32x16_bf16(ah, bh, acc[nt], 0, 0, 0);
      acc[nt] = __builtin_amdgcn_mfma_f32_32x32x16_bf16(al, bh, acc[nt], 0, 0, 0);
      acc[nt] = __builtin_amdgcn_mfma_f32_32x32x16_bf16(ah, bl, acc[nt], 0, 0, 0);
    }
    a0 = na0;
    a1 = na1;
    if (s + 1 < NCHUNK) block_sync_lds();  // LDS-only drain
  }

  // epilogue: bias + relu + coalesced atomics from C layout
  // (col=lane&31, row=(r&3)+8*(r>>2)+4*half -- HW-verified 32x32 C/D mapping)
  float bias[4];
#pragma unroll
  for (int nt = 0; nt < 4; ++nt) bias[nt] = bm[nt * 32 + m];
#pragma unroll
  for (int nt = 0; nt < 4; ++nt) {
#pragma unroll
    for (int r = 0; r < 16; ++r) {
      int row = (r & 3) + 8 * (r >> 2) + 4 * half;
      int el = wid * 32 + row;
      float v = fmaxf(acc[nt][r] + bias[nt], 0.f);
      unsafeAtomicAdd(&aggrH[(size_t)dstS[el] * H + nt * 32 + m], v);
    }
  }
}

// ---------------- fused node update ----------------
__global__ __launch_bounds__(256) void node_update_kernel(
    float* __restrict__ h, const float* __restrict__ aggrH,
    const int* __restrict__ deg, const float* __restrict__ Wu,
    const float* __restrict__ va, const float* __restrict__ ub1,
    const float* __restrict__ uW2, const float* __restrict__ ub2) {
  __shared__ float ins[16][256];  // [h(128) | aggrH(128)]
  __shared__ float ts[16][128];
  __shared__ float degS[16];
  int tid = threadIdx.x;
  int nbase = blockIdx.x * 16;
  if (tid < 16) degS[tid] = (float)deg[nbase + tid];
#pragma unroll
  for (int t = 0; t < 4; ++t) {
    int f = tid + t * 256;
    int r = f >> 5, c4 = f & 31;
    const float* s = (r < 16) ? (h + (size_t)(nbase + r) * H)
                              : (aggrH + (size_t)(nbase + r - 16) * H);
    float4 v = ((const float4*)s)[c4];
    float* q = (r < 16) ? &ins[r][c4 * 4] : &ins[r - 16][H + c4 * 4];
    *(float4*)q = v;
  }
  __syncthreads();
  int j = tid & 127;
  int n0 = (tid >> 7) * 8;
  float acc[8];
  {
    float b = ub1[j], vaj = va[j];
#pragma unroll
    for (int e = 0; e < 8; ++e) acc[e] = fmaf(degS[n0 + e], vaj, b);
  }
  for (int k = 0; k < 256; k += 4) {
    float w0 = Wu[(size_t)(k + 0) * H + j];
    float w1 = Wu[(size_t)(k + 1) * H + j];
    float w2 = Wu[(size_t)(k + 2) * H + j];
    float w3 = Wu[(size_t)(k + 3) * H + j];
#pragma unroll
    for (int e = 0; e < 8; ++e) {
      float4 v = *(const float4*)&ins[n0 + e][k];
      acc[e] = fmaf(v.x, w0, acc[e]);
      acc[e] = fmaf(v.y, w1, acc[e]);
      acc[e] = fmaf(v.z, w2, acc[e]);
      acc[e] = fmaf(v.w, w3, acc[e]);
    }
  }
#pragma unroll
  for (int e = 0; e < 8; ++e) ts[n0 + e][j] = fmaxf(acc[e], 0.f);
  __syncthreads();
  {
    float b2 = ub2[j];
#pragma unroll
    for (int e = 0; e < 8; ++e) acc[e] = b2;
  }
  for (int k = 0; k < 128; k += 4) {
    float w0 = uW2[(size_t)(k + 0) * H + j];
    float w1 = uW2[(size_t)(k + 1) * H + j];
    float w2 = uW2[(size_t)(k + 2) * H + j];
    float w3 = uW2[(size_t)(k + 3) * H + j];
#pragma unroll
    for (int e = 0; e < 8; ++e) {
      float4 v = *(const float4*)&ts[n0 + e][k];
      acc[e] = fmaf(v.x, w0, acc[e]);
      acc[e] = fmaf(v.y, w1, acc[e]);
      acc[e] = fmaf(v.z, w2, acc[e]);
      acc[e] = fmaf(v.w, w3, acc[e]);
    }
  }
#pragma unroll
  for (int e = 0; e < 8; ++e) {
    size_t idx = (size_t)(nbase + n0 + e) * H + j;
    h[idx] += acc[e];
  }
}

// ---------------- batch mean pooling (batch is sorted) ----------------
__global__ __launch_bounds__(128) void pool_kernel(
    const float* __restrict__ h, const int* __restrict__ batch,
    float* __restrict__ pooled, int* __restrict__ counts) {
  int j = threadIdx.x;
  int nbase = blockIdx.x * 128;
  int nend = nbase + 128;
  if (nend > NN) nend = NN;
  int cur = batch[nbase];
  float sum = 0.f;
  int cnt = 0;
  for (int n = nbase; n < nend; ++n) {
    int b = batch[n];
    if (b != cur) {
      unsafeAtomicAdd(&pooled[cur * H + j], sum);
      if (j == 0) atomicAdd(&counts[cur], cnt);
      sum = 0.f; cnt = 0; cur = b;
    }
    sum += h[(size_t)n * H + j];
    cnt++;
  }
  unsafeAtomicAdd(&pooled[cur * H + j], sum);
  if (j == 0) atomicAdd(&counts[cur], cnt);
}

// ---------------- readout MLP ----------------
__global__ __launch_bounds__(128) void readout_kernel(
    const float* __restrict__ pooled, const int* __restrict__ counts,
    const float* __restrict__ gf, const float* __restrict__ Wg,
    const float* __restrict__ bg, const float* __restrict__ rW1,
    const float* __restrict__ rb1, const float* __restrict__ rW2,
    const float* __restrict__ rb2, const float* __restrict__ rW3,
    const float* __restrict__ rb3, float* __restrict__ out) {
  __shared__ float fin[256];
  __shared__ float t1[128];
  __shared__ float t2[64];
  int j = threadIdx.x;
  for (int b = 0; b < NBATCH; ++b) {
    float cnt = (float)counts[b];
    if (cnt < 1.f) cnt = 1.f;
    fin[j] = pooled[b * H + j] / cnt;
    fin[H + j] = fmaf(gf[b], Wg[j], bg[j]);
    __syncthreads();
    float a = rb1[j];
    for (int k = 0; k < 256; ++k) a = fmaf(fin[k], rW1[k * H + j], a);
    t1[j] = fmaxf(a, 0.f);
    __syncthreads();
    if (j < 64) {
      float a2 = rb2[j];
      for (int k = 0; k < 128; ++k) a2 = fmaf(t1[k], rW2[k * 64 + j], a2);
      t2[j] = fmaxf(a2, 0.f);
    }
    __syncthreads();
    if (j < 64) {
      float p = t2[j] * rW3[j];
#pragma unroll
      for (int off = 32; off; off >>= 1) p += __shfl_down(p, off);
      if (j == 0) out[b] = p + rb3[0];
    }
    __syncthreads();
  }
}

extern "C" void kernel_launch(void* const* d_in, const int* in_sizes, int n_in,
                              void* d_out, int out_size, void* d_ws, size_t ws_size,
                              hipStream_t stream) {
  const float* x   = (const float*)d_in[0];
  const float* ea  = (const float*)d_in[1];
  const float* gf  = (const float*)d_in[2];
  const int*   ei  = (const int*)d_in[3];
  const int*   bat = (const int*)d_in[4];
  const float* Wn  = (const float*)d_in[5];
  const float* bn  = (const float*)d_in[6];
  const float* We  = (const float*)d_in[7];
  const float* be  = (const float*)d_in[8];
  const float* Wg  = (const float*)d_in[9];
  const float* bg  = (const float*)d_in[10];
  const float* mW1 = (const float*)d_in[11];
  const float* mb1 = (const float*)d_in[12];
  const float* mW2 = (const float*)d_in[13];
  const float* mb2 = (const float*)d_in[14];
  const float* uW1 = (const float*)d_in[15];
  const float* ub1 = (const float*)d_in[16];
  const float* uW2 = (const float*)d_in[17];
  const float* ub2 = (const float*)d_in[18];
  const float* rW1 = (const float*)d_in[19];
  const float* rb1 = (const float*)d_in[20];
  const float* rW2 = (const float*)d_in[21];
  const float* rb2 = (const float*)d_in[22];
  const float* rW3 = (const float*)d_in[23];
  const float* rb3 = (const float*)d_in[24];

  char* p = (char*)d_ws;
  float*  h     = (float*)p;  p += (size_t)NN * H * 4;         // 25.6 MB
  float*  aggrH = (float*)p;  p += (size_t)NN * H * 4;         // 25.6 MB
  __bf16* WtS   = (__bf16*)p; p += (size_t)NLAYERS * NCHUNK * CHUNK_ELEMS * 2;  // 418 KB
  float*  bm    = (float*)p;  p += (size_t)NLAYERS * H * 4;
  float*  Wu    = (float*)p;  p += (size_t)NLAYERS * 256 * H * 4;
  float*  va    = (float*)p;  p += (size_t)NLAYERS * H * 4;
  int*    deg   = (int*)p;    p += (size_t)NN * 4;
  float*  pooled= (float*)p;  p += (size_t)NBATCH * H * 4;
  int*    counts= (int*)p;    p += 64;

  hipMemsetAsync(deg, 0, (size_t)NN * 4, stream);
  hipMemsetAsync(pooled, 0, (size_t)NBATCH * H * 4, stream);
  hipMemsetAsync(counts, 0, 64, stream);

  embed_nodes_kernel<<<NN / 16, 128, 0, stream>>>(x, Wn, bn, h);
  degree_kernel<<<(NE + 255) / 256, 256, 0, stream>>>(ei, deg);
  precomp_wt_kernel<<<NLAYERS * 18, 256, 0, stream>>>(mW1, mb1, We, be, WtS, bm);
  precomp_wu_kernel<<<NLAYERS * 257, 128, 0, stream>>>(uW1, mW2, mb2, Wu, va);

  for (int l = 0; l < NLAYERS; ++l) {
    hipMemsetAsync(aggrH, 0, (size_t)NN * H * 4, stream);
    edge_mlp_kernel<<<NE / EPB, 256, 0, stream>>>(
        h, ei, ea, WtS + (size_t)l * NCHUNK * CHUNK_ELEMS,
        bm + (size_t)l * H, aggrH);
    node_update_kernel<<<NN / 16, 256, 0, stream>>>(
        h, aggrH, deg, Wu + (size_t)l * 256 * H, va + (size_t)l * H,
        ub1 + (size_t)l * H, uW2 + (size_t)l * H * H, ub2 + (size_t)l * H);
  }

  pool_kernel<<<(NN + 127) / 128, 128, 0, stream>>>(h, bat, pooled, counts);
  readout_kernel<<<1, 128, 0, stream>>>(pooled, counts, gf, Wg, bg, rW1, rb1,
                                        rW2, rb2, rW3, rb3, (float*)d_out);
}

// Round 7
// 980.994 us; speedup vs baseline: 2.9137x; 1.1869x over previous
//
#include <hip/hip_runtime.h>

#define NN 50000
#define NPAD 50048     // 391 * 128, padded node count for MFMA node kernel
#define NBLK 391
#define NE 400000
#define NBATCH 8
#define NDIM 32
#define EDIM 16
#define H 128
#define NLAYERS 3
#define EPB 128   // edges per block in edge_mlp (4 waves x 32 edges)
#define KTOT 272  // folded K: 128 dst + 128 src + 16 edge-attr
#define NCHUNK 17 // edge K chunks of 16
#define CHUNK_ELEMS 4096  // 2 hilo * 4 nt * 64 lane * 8 = bf16 elems per chunk
#define NODE_CHUNKS 24    // 16 (Wu, K=256) + 8 (uW2, K=128)

typedef __attribute__((ext_vector_type(8))) __bf16 bf16x8;
typedef __attribute__((ext_vector_type(16))) float f32x16;
typedef __attribute__((ext_vector_type(8))) short short8;

// barrier that drains LDS only -- leaves global loads in flight
__device__ __forceinline__ void block_sync_lds() {
  asm volatile("s_waitcnt lgkmcnt(0)\ns_barrier" ::: "memory");
}
__device__ __forceinline__ void wait_lds() {
  asm volatile("s_waitcnt lgkmcnt(0)" ::: "memory");
}

// ---------------- node embedding: h = x @ Wn + bn ----------------
__global__ __launch_bounds__(128) void embed_nodes_kernel(
    const float* __restrict__ x, const float* __restrict__ Wn,
    const float* __restrict__ bn, float* __restrict__ h) {
  __shared__ float Ws[NDIM * H];
  __shared__ float xs[16 * NDIM];
  int j = threadIdx.x;
  int nbase = blockIdx.x * 16;
  for (int r = 0; r < NDIM; ++r) Ws[r * H + j] = Wn[r * H + j];
#pragma unroll
  for (int t = 0; t < 4; ++t) {
    int f = j + t * 128;
    xs[f] = x[nbase * NDIM + f];
  }
  __syncthreads();
  float b = bn[j];
  for (int nn = 0; nn < 16; ++nn) {
    float acc = b;
#pragma unroll
    for (int k = 0; k < NDIM; ++k)
      acc = fmaf(xs[nn * NDIM + k], Ws[k * H + j], acc);
    h[(size_t)(nbase + nn) * H + j] = acc;
  }
}

// ---------------- degree histogram over dst ----------------
__global__ __launch_bounds__(256) void degree_kernel(const int* __restrict__ ei,
                                                     int* __restrict__ deg) {
  int e = blockIdx.x * 256 + threadIdx.x;
  if (e < NE) atomicAdd(&deg[ei[NE + e]], 1);
}

// ---------------- precompute folded+split edge weights, MFMA-frag-swizzled ----------------
__global__ __launch_bounds__(256) void precomp_wt_kernel(
    const float* __restrict__ mW1, const float* __restrict__ mb1,
    const float* __restrict__ We, const float* __restrict__ be,
    __bf16* __restrict__ WtS, float* __restrict__ bm) {
  int l = blockIdx.x / 18;
  int c = blockIdx.x % 18;
  int tid = threadIdx.x;
  const float* w1 = mW1 + (size_t)l * 384 * H;
  if (c == 17) {
    if (tid < 128) {
      float s = mb1[l * H + tid];
      for (int q = 0; q < 128; ++q)
        s = fmaf(be[q], w1[(size_t)(256 + q) * H + tid], s);
      bm[l * H + tid] = s;
    }
    return;
  }
  int nt = tid >> 6, lane = tid & 63;
  int n = nt * 32 + (lane & 31);
  int half = lane >> 5;
  __bf16* dst = WtS + ((size_t)l * NCHUNK + c) * CHUNK_ELEMS;
#pragma unroll
  for (int j = 0; j < 8; ++j) {
    int k = c * 16 + half * 8 + j;
    float w;
    if (k < 256) {
      w = w1[(size_t)k * H + n];
    } else {
      int i = k - 256;
      float s = 0.f;
      for (int q = 0; q < 128; ++q)
        s = fmaf(We[i * H + q], w1[(size_t)(256 + q) * H + n], s);
      w = s;
    }
    __bf16 hi = (__bf16)w;
    __bf16 lo = (__bf16)(w - (float)hi);
    dst[((0 * 4 + nt) * 64 + lane) * 8 + j] = hi;
    dst[((1 * 4 + nt) * 64 + lane) * 8 + j] = lo;
  }
}

// ---------------- precompute folded update weights (fp32 Wu) ----------------
__global__ __launch_bounds__(128) void precomp_wu_kernel(
    const float* __restrict__ uW1, const float* __restrict__ mW2,
    const float* __restrict__ mb2, float* __restrict__ Wu,
    float* __restrict__ va) {
  int l = blockIdx.x / 257;
  int r = blockIdx.x % 257;
  int j = threadIdx.x;
  const float* u1 = uW1 + (size_t)l * 256 * H;
  if (r < 128) {
    Wu[((size_t)l * 256 + r) * H + j] = u1[(size_t)r * H + j];
  } else if (r < 256) {
    int i = r - 128;
    const float* m2 = mW2 + ((size_t)l * H + i) * H;
    float s = 0.f;
    for (int c = 0; c < H; ++c)
      s = fmaf(m2[c], u1[(size_t)(128 + c) * H + j], s);
    Wu[((size_t)l * 256 + r) * H + j] = s;
  } else {
    float s = 0.f;
    for (int c = 0; c < H; ++c)
      s = fmaf(mb2[l * H + c], u1[(size_t)(128 + c) * H + j], s);
    va[l * H + j] = s;
  }
}

// ---------------- swizzle node weights (Wu fp32 + uW2) into hi/lo frag chunks ----------------
// WnS[l][c][hilo][nt][lane][8], c<16: Wu[k=c*16+...][n]; c>=16: uW2[k=(c-16)*16+...][n]
__global__ __launch_bounds__(256) void precomp_wns_kernel(
    const float* __restrict__ Wu, const float* __restrict__ uW2,
    __bf16* __restrict__ WnS) {
  int l = blockIdx.x / NODE_CHUNKS;
  int c = blockIdx.x % NODE_CHUNKS;
  int tid = threadIdx.x;
  int nt = tid >> 6, lane = tid & 63;
  int n = nt * 32 + (lane & 31);
  int half = lane >> 5;
  __bf16* dst = WnS + ((size_t)l * NODE_CHUNKS + c) * CHUNK_ELEMS;
#pragma unroll
  for (int j = 0; j < 8; ++j) {
    float w;
    if (c < 16) {
      int k = c * 16 + half * 8 + j;
      w = Wu[((size_t)l * 256 + k) * H + n];
    } else {
      int k = (c - 16) * 16 + half * 8 + j;
      w = uW2[((size_t)l * H + k) * H + n];
    }
    __bf16 hi = (__bf16)w;
    __bf16 lo = (__bf16)(w - (float)hi);
    dst[((0 * 4 + nt) * 64 + lane) * 8 + j] = hi;
    dst[((1 * 4 + nt) * 64 + lane) * 8 + j] = lo;
  }
}

// ---------------- MFMA edge MLP + scatter-add of relu(hidden) ----------------
__global__ __launch_bounds__(256) void edge_mlp_kernel(
    const float* __restrict__ h, const int* __restrict__ ei,
    const float* __restrict__ ea, const __bf16* __restrict__ WtS,
    const float* __restrict__ bm, float* __restrict__ aggrH) {
  __shared__ __bf16 Bt[2][CHUNK_ELEMS];  // dbuf x 8KB
  __shared__ int dstS[EPB];
  int tid = threadIdx.x;
  int ebase = blockIdx.x * EPB;
  if (tid < EPB) dstS[tid] = ei[NE + ebase + tid];
  int wid = tid >> 6, lane = tid & 63;
  int m = lane & 31, half = lane >> 5;
  int edge = ebase + wid * 32 + m;
  int srcN = ei[edge];
  const short8* gW = (const short8*)WtS;
  short8* sB0 = (short8*)&Bt[0][0];
  short8* sB1 = (short8*)&Bt[1][0];
  {
    short8 c00 = gW[tid], c01 = gW[tid + 256];
    sB0[tid] = c00;
    sB0[tid + 256] = c01;
  }
  short8 p0 = gW[512 + tid], p1 = gW[512 + tid + 256];
  block_sync_lds();
  int dstN = dstS[wid * 32 + m];
  const float* aDst = h + (size_t)dstN * H + half * 8;
  const float* aSrc = h + (size_t)srcN * H + half * 8;
  const float* aEa = ea + (size_t)edge * EDIM + half * 8;

  f32x16 acc[4];
#pragma unroll
  for (int nt = 0; nt < 4; ++nt)
#pragma unroll
    for (int r = 0; r < 16; ++r) acc[nt][r] = 0.f;

  float4 a0 = *(const float4*)aDst;
  float4 a1 = *(const float4*)(aDst + 4);

  for (int s = 0; s < NCHUNK; ++s) {
    int buf = s & 1;
    float4 na0 = a0, na1 = a1;
    if (s + 1 < NCHUNK) {
      int sp = s + 1;
      const float* pp = (sp < 8) ? (aDst + sp * 16)
                      : (sp < 16) ? (aSrc + (sp - 8) * 16) : aEa;
      na0 = *(const float4*)pp;
      na1 = *(const float4*)(pp + 4);
    }
    if (s + 1 < NCHUNK) {
      short8* sb = buf ? sB0 : sB1;
      sb[tid] = p0;
      sb[tid + 256] = p1;
      if (s + 2 < NCHUNK) {
        p0 = gW[(size_t)(s + 2) * 512 + tid];
        p1 = gW[(size_t)(s + 2) * 512 + tid + 256];
      }
    }
    float af[8] = {a0.x, a0.y, a0.z, a0.w, a1.x, a1.y, a1.z, a1.w};
    bf16x8 ah, al;
#pragma unroll
    for (int j = 0; j < 8; ++j) {
      __bf16 hi = (__bf16)af[j];
      ah[j] = hi;
      al[j] = (__bf16)(af[j] - (float)hi);
    }
    const __bf16* bb = &Bt[buf][0];
#pragma unroll
    for (int nt = 0; nt < 4; ++nt) {
      bf16x8 bh = *(const bf16x8*)&bb[((0 * 4 + nt) * 64 + lane) * 8];
      bf16x8 bl = *(const bf16x8*)&bb[((1 * 4 + nt) * 64 + lane) * 8];
      acc[nt] = __builtin_amdgcn_mfma_f32_32x32x16_bf16(ah, bh, acc[nt], 0, 0, 0);
      acc[nt] = __builtin_amdgcn_mfma_f32_32x32x16_bf16(al, bh, acc[nt], 0, 0, 0);
      acc[nt] = __builtin_amdgcn_mfma_f32_32x32x16_bf16(ah, bl, acc[nt], 0, 0, 0);
    }
    a0 = na0;
    a1 = na1;
    if (s + 1 < NCHUNK) block_sync_lds();
  }

  float bias[4];
#pragma unroll
  for (int nt = 0; nt < 4; ++nt) bias[nt] = bm[nt * 32 + m];
#pragma unroll
  for (int nt = 0; nt < 4; ++nt) {
#pragma unroll
    for (int r = 0; r < 16; ++r) {
      int row = (r & 3) + 8 * (r >> 2) + 4 * half;
      int el = wid * 32 + row;
      float v = fmaxf(acc[nt][r] + bias[nt], 0.f);
      unsafeAtomicAdd(&aggrH[(size_t)dstS[el] * H + nt * 32 + m], v);
    }
  }
}

// ---------------- MFMA fused node update ----------------
// 128 nodes/block (padded grid), 4 waves x (32 rows x 128 cols).
// GEMM1: [h|aggr] (K=256) @ Wu -> relu(+ub1+deg*va) -> hid (bf16, per-wave LDS)
// GEMM2: hid (K=128) @ uW2 -> h += (+ub2).  B hi/lo split (2 MFMA/tile),
// A plain bf16 (random rounding, pooled away). Same 2-deep pipeline as edge.
__global__ __launch_bounds__(256) void node_update_mfma_kernel(
    float* __restrict__ h, const float* __restrict__ aggrH,
    const int* __restrict__ deg, const __bf16* __restrict__ WnS,
    const float* __restrict__ ub1, const float* __restrict__ va,
    const float* __restrict__ ub2) {
  __shared__ __bf16 Bt[2][CHUNK_ELEMS];   // 16 KB
  __shared__ __bf16 hid[4][32][132];      // 33.8 KB, stride 132 => 2-way alias (free)
  __shared__ float degS[128];
  int tid = threadIdx.x;
  int nb = blockIdx.x * 128;
  if (tid < 128) degS[tid] = (float)deg[nb + tid];
  int wid = tid >> 6, lane = tid & 63, m = lane & 31, half = lane >> 5;
  int row = nb + wid * 32 + m;
  const float* aH = h + (size_t)row * H + half * 8;
  const float* aG = aggrH + (size_t)row * H + half * 8;
  const short8* gW = (const short8*)WnS;
  short8* sB0 = (short8*)&Bt[0][0];
  short8* sB1 = (short8*)&Bt[1][0];
  sB0[tid] = gW[tid];
  sB0[tid + 256] = gW[tid + 256];
  short8 p0 = gW[512 + tid], p1 = gW[512 + tid + 256];
  float bv1[4], bva[4];
#pragma unroll
  for (int nt = 0; nt < 4; ++nt) {
    bv1[nt] = ub1[nt * 32 + m];
    bva[nt] = va[nt * 32 + m];
  }
  f32x16 acc[4];
#pragma unroll
  for (int nt = 0; nt < 4; ++nt)
#pragma unroll
    for (int r = 0; r < 16; ++r) acc[nt][r] = 0.f;
  float4 a0 = *(const float4*)aH;
  float4 a1 = *(const float4*)(aH + 4);
  block_sync_lds();

  // ---- GEMM1: chunks 0..15 ----
  for (int s = 0; s < 16; ++s) {
    int buf = s & 1;
    float4 na0 = a0, na1 = a1;
    if (s + 1 < 16) {
      int sp = s + 1;
      const float* pp = (sp < 8) ? (aH + sp * 16) : (aG + (sp - 8) * 16);
      na0 = *(const float4*)pp;
      na1 = *(const float4*)(pp + 4);
    }
    {
      short8* sb = buf ? sB0 : sB1;
      sb[tid] = p0;
      sb[tid + 256] = p1;
      if (s + 2 < NODE_CHUNKS) {
        p0 = gW[(size_t)(s + 2) * 512 + tid];
        p1 = gW[(size_t)(s + 2) * 512 + tid + 256];
      }
    }
    float af[8] = {a0.x, a0.y, a0.z, a0.w, a1.x, a1.y, a1.z, a1.w};
    bf16x8 ah;
#pragma unroll
    for (int j = 0; j < 8; ++j) ah[j] = (__bf16)af[j];
    const __bf16* bb = &Bt[buf][0];
#pragma unroll
    for (int nt = 0; nt < 4; ++nt) {
      bf16x8 bh = *(const bf16x8*)&bb[((0 * 4 + nt) * 64 + lane) * 8];
      bf16x8 bl = *(const bf16x8*)&bb[((1 * 4 + nt) * 64 + lane) * 8];
      acc[nt] = __builtin_amdgcn_mfma_f32_32x32x16_bf16(ah, bh, acc[nt], 0, 0, 0);
      acc[nt] = __builtin_amdgcn_mfma_f32_32x32x16_bf16(ah, bl, acc[nt], 0, 0, 0);
    }
    a0 = na0;
    a1 = na1;
    block_sync_lds();
  }

  // ---- epilogue1: bias + deg*va + relu -> hid (bf16) ----
#pragma unroll
  for (int nt = 0; nt < 4; ++nt) {
#pragma unroll
    for (int r = 0; r < 16; ++r) {
      int rowi = (r & 3) + 8 * (r >> 2) + 4 * half;
      float v = acc[nt][r] + bv1[nt] + degS[wid * 32 + rowi] * bva[nt];
      hid[wid][rowi][nt * 32 + m] = (__bf16)fmaxf(v, 0.f);
      acc[nt][r] = 0.f;
    }
  }
  wait_lds();  // own-wave hid writes must land before hid reads below

  // ---- GEMM2: chunks 16..23 ----
  for (int s = 16; s < NODE_CHUNKS; ++s) {
    int buf = s & 1;
    if (s + 1 < NODE_CHUNKS) {
      short8* sb = buf ? sB0 : sB1;
      sb[tid] = p0;
      sb[tid + 256] = p1;
      if (s + 2 < NODE_CHUNKS) {
        p0 = gW[(size_t)(s + 2) * 512 + tid];
        p1 = gW[(size_t)(s + 2) * 512 + tid + 256];
      }
    }
    bf16x8 ah = *(const bf16x8*)&hid[wid][m][(s - 16) * 16 + half * 8];
    const __bf16* bb = &Bt[buf][0];
#pragma unroll
    for (int nt = 0; nt < 4; ++nt) {
      bf16x8 bh = *(const bf16x8*)&bb[((0 * 4 + nt) * 64 + lane) * 8];
      bf16x8 bl = *(const bf16x8*)&bb[((1 * 4 + nt) * 64 + lane) * 8];
      acc[nt] = __builtin_amdgcn_mfma_f32_32x32x16_bf16(ah, bh, acc[nt], 0, 0, 0);
      acc[nt] = __builtin_amdgcn_mfma_f32_32x32x16_bf16(ah, bl, acc[nt], 0, 0, 0);
    }
    if (s + 1 < NODE_CHUNKS) block_sync_lds();
  }

  // ---- epilogue2: h += upd + ub2 ----
#pragma unroll
  for (int nt = 0; nt < 4; ++nt) {
    float b2 = ub2[nt * 32 + m];
#pragma unroll
    for (int r = 0; r < 16; ++r) {
      int rowi = (r & 3) + 8 * (r >> 2) + 4 * half;
      float* hp = h + (size_t)(nb + wid * 32 + rowi) * H + nt * 32 + m;
      *hp += acc[nt][r] + b2;
    }
  }
}

// ---------------- batch mean pooling (batch is sorted) ----------------
__global__ __launch_bounds__(128) void pool_kernel(
    const float* __restrict__ h, const int* __restrict__ batch,
    float* __restrict__ pooled, int* __restrict__ counts) {
  int j = threadIdx.x;
  int nbase = blockIdx.x * 128;
  int nend = nbase + 128;
  if (nend > NN) nend = NN;
  if (nbase >= NN) return;
  int cur = batch[nbase];
  float sum = 0.f;
  int cnt = 0;
  for (int n = nbase; n < nend; ++n) {
    int b = batch[n];
    if (b != cur) {
      unsafeAtomicAdd(&pooled[cur * H + j], sum);
      if (j == 0) atomicAdd(&counts[cur], cnt);
      sum = 0.f; cnt = 0; cur = b;
    }
    sum += h[(size_t)n * H + j];
    cnt++;
  }
  unsafeAtomicAdd(&pooled[cur * H + j], sum);
  if (j == 0) atomicAdd(&counts[cur], cnt);
}

// ---------------- readout MLP ----------------
__global__ __launch_bounds__(128) void readout_kernel(
    const float* __restrict__ pooled, const int* __restrict__ counts,
    const float* __restrict__ gf, const float* __restrict__ Wg,
    const float* __restrict__ bg, const float* __restrict__ rW1,
    const float* __restrict__ rb1, const float* __restrict__ rW2,
    const float* __restrict__ rb2, const float* __restrict__ rW3,
    const float* __restrict__ rb3, float* __restrict__ out) {
  __shared__ float fin[256];
  __shared__ float t1[128];
  __shared__ float t2[64];
  int j = threadIdx.x;
  for (int b = 0; b < NBATCH; ++b) {
    float cnt = (float)counts[b];
    if (cnt < 1.f) cnt = 1.f;
    fin[j] = pooled[b * H + j] / cnt;
    fin[H + j] = fmaf(gf[b], Wg[j], bg[j]);
    __syncthreads();
    float a = rb1[j];
    for (int k = 0; k < 256; ++k) a = fmaf(fin[k], rW1[k * H + j], a);
    t1[j] = fmaxf(a, 0.f);
    __syncthreads();
    if (j < 64) {
      float a2 = rb2[j];
      for (int k = 0; k < 128; ++k) a2 = fmaf(t1[k], rW2[k * 64 + j], a2);
      t2[j] = fmaxf(a2, 0.f);
    }
    __syncthreads();
    if (j < 64) {
      float p = t2[j] * rW3[j];
#pragma unroll
      for (int off = 32; off; off >>= 1) p += __shfl_down(p, off);
      if (j == 0) out[b] = p + rb3[0];
    }
    __syncthreads();
  }
}

extern "C" void kernel_launch(void* const* d_in, const int* in_sizes, int n_in,
                              void* d_out, int out_size, void* d_ws, size_t ws_size,
                              hipStream_t stream) {
  const float* x   = (const float*)d_in[0];
  const float* ea  = (const float*)d_in[1];
  const float* gf  = (const float*)d_in[2];
  const int*   ei  = (const int*)d_in[3];
  const int*   bat = (const int*)d_in[4];
  const float* Wn  = (const float*)d_in[5];
  const float* bn  = (const float*)d_in[6];
  const float* We  = (const float*)d_in[7];
  const float* be  = (const float*)d_in[8];
  const float* Wg  = (const float*)d_in[9];
  const float* bg  = (const float*)d_in[10];
  const float* mW1 = (const float*)d_in[11];
  const float* mb1 = (const float*)d_in[12];
  const float* mW2 = (const float*)d_in[13];
  const float* mb2 = (const float*)d_in[14];
  const float* uW1 = (const float*)d_in[15];
  const float* ub1 = (const float*)d_in[16];
  const float* uW2 = (const float*)d_in[17];
  const float* ub2 = (const float*)d_in[18];
  const float* rW1 = (const float*)d_in[19];
  const float* rb1 = (const float*)d_in[20];
  const float* rW2 = (const float*)d_in[21];
  const float* rb2 = (const float*)d_in[22];
  const float* rW3 = (const float*)d_in[23];
  const float* rb3 = (const float*)d_in[24];

  char* p = (char*)d_ws;
  float*  h     = (float*)p;  p += (size_t)NPAD * H * 4;
  float*  aggrH = (float*)p;  p += (size_t)NPAD * H * 4;
  __bf16* WtS   = (__bf16*)p; p += (size_t)NLAYERS * NCHUNK * CHUNK_ELEMS * 2;
  __bf16* WnS   = (__bf16*)p; p += (size_t)NLAYERS * NODE_CHUNKS * CHUNK_ELEMS * 2;
  float*  bm    = (float*)p;  p += (size_t)NLAYERS * H * 4;
  float*  Wu    = (float*)p;  p += (size_t)NLAYERS * 256 * H * 4;
  float*  va    = (float*)p;  p += (size_t)NLAYERS * H * 4;
  int*    deg   = (int*)p;    p += (size_t)NPAD * 4;
  float*  pooled= (float*)p;  p += (size_t)NBATCH * H * 4;
  int*    counts= (int*)p;    p += 64;

  hipMemsetAsync(deg, 0, (size_t)NPAD * 4, stream);
  hipMemsetAsync(pooled, 0, (size_t)NBATCH * H * 4, stream);
  hipMemsetAsync(counts, 0, 64, stream);

  embed_nodes_kernel<<<NN / 16, 128, 0, stream>>>(x, Wn, bn, h);
  degree_kernel<<<(NE + 255) / 256, 256, 0, stream>>>(ei, deg);
  precomp_wt_kernel<<<NLAYERS * 18, 256, 0, stream>>>(mW1, mb1, We, be, WtS, bm);
  precomp_wu_kernel<<<NLAYERS * 257, 128, 0, stream>>>(uW1, mW2, mb2, Wu, va);
  precomp_wns_kernel<<<NLAYERS * NODE_CHUNKS, 256, 0, stream>>>(Wu, uW2, WnS);

  for (int l = 0; l < NLAYERS; ++l) {
    hipMemsetAsync(aggrH, 0, (size_t)NPAD * H * 4, stream);
    edge_mlp_kernel<<<NE / EPB, 256, 0, stream>>>(
        h, ei, ea, WtS + (size_t)l * NCHUNK * CHUNK_ELEMS,
        bm + (size_t)l * H, aggrH);
    node_update_mfma_kernel<<<NBLK, 256, 0, stream>>>(
        h, aggrH, deg, WnS + (size_t)l * NODE_CHUNKS * CHUNK_ELEMS,
        ub1 + (size_t)l * H, va + (size_t)l * H, ub2 + (size_t)l * H);
  }

  pool_kernel<<<(NN + 127) / 128, 128, 0, stream>>>(h, bat, pooled, counts);
  readout_kernel<<<1, 128, 0, stream>>>(pooled, counts, gf, Wg, bg, rW1, rb1,
                                        rW2, rb2, rW3, rb3, (float*)d_out);
}